// Round 8
// baseline (1308.147 us; speedup 1.0000x reference)
//
#include <hip/hip_runtime.h>
#include <hip/hip_bf16.h>

#define D_IN 64
#define D_EMB 128
#define GI 192           // D_IN + D_EMB
#define H1 32
#define H2 8

typedef __attribute__((ext_vector_type(8))) short bf16x8;
typedef __attribute__((ext_vector_type(4))) float f32x4;

__device__ __forceinline__ unsigned short f2bf(float f) {
    unsigned int u = __float_as_uint(f);
    return (unsigned short)((u + 0x7fffu + ((u >> 16) & 1u)) >> 16);
}
__device__ __forceinline__ float bflo(unsigned int u) { return __uint_as_float(u << 16); }
__device__ __forceinline__ float bfhi(unsigned int u) { return __uint_as_float(u & 0xffff0000u); }
__device__ __forceinline__ unsigned int pk2(unsigned short a, unsigned short b) {
    return (unsigned int)a | ((unsigned int)b << 16);
}

// ---------------------------------------------------------------------------
// CSR build, XCD-partitioned (round-3 notes: merges partial-line writes in L2)
// ---------------------------------------------------------------------------
__global__ __launch_bounds__(256) void hist_part_k(const int* __restrict__ dst, int* __restrict__ cnt,
                                                   int E, int N8) {
    int p = blockIdx.x & 7;
    int base = (blockIdx.x >> 3) * 1024;
    int lo = p * N8, hi = lo + N8;
    #pragma unroll
    for (int t = 0; t < 4; ++t) {
        int e = base + t * 256 + threadIdx.x;
        if (e < E) {
            int d = dst[e];
            if (d >= lo && d < hi) atomicAdd(&cnt[d], 1);
        }
    }
}

__global__ __launch_bounds__(256) void scan1_k(const int* __restrict__ cnt, int* __restrict__ loc,
                                               int* __restrict__ bsum, int N) {
    __shared__ int s[256];
    int tid = threadIdx.x;
    int i = blockIdx.x * 256 + tid;
    int v = (i < N) ? cnt[i] : 0;
    s[tid] = v;
    __syncthreads();
    #pragma unroll
    for (int off = 1; off < 256; off <<= 1) {
        int u = (tid >= off) ? s[tid - off] : 0;
        __syncthreads();
        s[tid] += u;
        __syncthreads();
    }
    int incl = s[tid];
    if (i < N) loc[i] = incl - v;
    if (tid == 255) bsum[blockIdx.x] = incl;
}

__global__ __launch_bounds__(512) void scan2_k(int* __restrict__ bsum, int NB) {
    __shared__ int s[512];
    int tid = threadIdx.x;
    int v = (tid < NB) ? bsum[tid] : 0;
    s[tid] = v;
    __syncthreads();
    #pragma unroll
    for (int off = 1; off < 512; off <<= 1) {
        int u = (tid >= off) ? s[tid - off] : 0;
        __syncthreads();
        s[tid] += u;
        __syncthreads();
    }
    if (tid < NB) bsum[tid] = s[tid] - v;
}

__global__ __launch_bounds__(256) void scan3_k(int* __restrict__ rp, const int* __restrict__ bsum,
                                               int* __restrict__ cursor, int N, int E) {
    int i = blockIdx.x * 256 + threadIdx.x;
    if (i < N) {
        int r = rp[i] + bsum[i >> 8];
        rp[i] = r;
        cursor[i] = r;
    } else if (i == N) {
        rp[N] = E;
    }
}

__global__ __launch_bounds__(256) void scatter_part_k(const int* __restrict__ src, const int* __restrict__ dst,
                                                      int* __restrict__ cursor, int* __restrict__ csr,
                                                      int E, int N8) {
    int p = blockIdx.x & 7;
    int base = (blockIdx.x >> 3) * 1024;
    int lo = p * N8, hi = lo + N8;
    #pragma unroll
    for (int t = 0; t < 4; ++t) {
        int e = base + t * 256 + threadIdx.x;
        if (e < E) {
            int d = dst[e];
            if (d >= lo && d < hi) {
                int s = src[e];
                int pos = atomicAdd(&cursor[d], 1);
                csr[pos] = s;
            }
        }
    }
}

// ---------------------------------------------------------------------------
// Conversions / weight fragment prep
// ---------------------------------------------------------------------------
__global__ __launch_bounds__(256) void xcvt_k(const float* __restrict__ x, unsigned short* __restrict__ xb,
                                              int total4) {
    int i = blockIdx.x * 256 + threadIdx.x;
    if (i < total4) {
        float4 v = ((const float4*)x)[i];
        ((uint2*)xb)[i] = make_uint2(pk2(f2bf(v.x), f2bf(v.y)), pk2(f2bf(v.z), f2bf(v.w)));
    }
}

__global__ __launch_bounds__(256) void wfrag_all_k(
    const float* __restrict__ W_in, const float* __restrict__ mlp_W1, const float* __restrict__ mlp_W2,
    const float* __restrict__ graph_W, const float* __restrict__ out_W,
    unsigned short* __restrict__ wf_in, unsigned short* __restrict__ wf_w1,
    unsigned short* __restrict__ wf_w2, unsigned short* __restrict__ wf_graph,
    unsigned short* __restrict__ wf_out) {
    int idx = blockIdx.x * 256 + threadIdx.x;
    const float* src;
    unsigned short* dst;
    int local;
    if (idx < 8192) { src = W_in; dst = wf_in; local = idx; }
    else if (idx < 81920) { int t = idx - 8192; int l = t / 24576; local = t - l * 24576;
                            src = mlp_W1 + (size_t)l * 24576; dst = wf_w1 + (size_t)l * 24576; }
    else if (idx < 131072) { int t = idx - 81920; int l = t / 16384; local = t - l * 16384;
                             src = mlp_W2 + (size_t)l * 16384; dst = wf_w2 + (size_t)l * 16384; }
    else if (idx < 147456) { local = idx - 131072; src = graph_W; dst = wf_graph; }
    else { local = idx - 147456; src = out_W; dst = wf_out; }
    int k = local >> 7, c = local & 127;
    dst[(((size_t)(k >> 3) * 128) + c) * 8 + (k & 7)] = f2bf(src[local]);
}

// ---------------------------------------------------------------------------
// x aggregation (layer-invariant), full-row gather, 4x unrolled (round-6 form)
// ---------------------------------------------------------------------------
__global__ __launch_bounds__(256) void agg64b_k(const unsigned short* __restrict__ xb,
                                                const int* __restrict__ rp, const int* __restrict__ cs,
                                                float* __restrict__ out, int N) {
    int n = blockIdx.x * 8 + (threadIdx.x >> 5);
    int lane = threadIdx.x & 31;
    if (n >= N) return;
    int bg = rp[n], e = rp[n + 1];
    const unsigned int* x2 = (const unsigned int*)xb;
    float sx = 0.f, sy = 0.f;
    int j = bg;
    for (; j + 3 < e; j += 4) {
        unsigned int v0 = x2[(size_t)cs[j] * 32 + lane];
        unsigned int v1 = x2[(size_t)cs[j + 1] * 32 + lane];
        unsigned int v2 = x2[(size_t)cs[j + 2] * 32 + lane];
        unsigned int v3 = x2[(size_t)cs[j + 3] * 32 + lane];
        sx += bflo(v0) + bflo(v1) + bflo(v2) + bflo(v3);
        sy += bfhi(v0) + bfhi(v1) + bfhi(v2) + bfhi(v3);
    }
    for (; j < e; ++j) {
        unsigned int v = x2[(size_t)cs[j] * 32 + lane];
        sx += bflo(v);
        sy += bfhi(v);
    }
    ((float2*)out)[(size_t)n * 32 + lane] = make_float2(sx, sy);
}

// ---------------------------------------------------------------------------
// Cross-wave LayerNorm epilogue for a 128x128 tile held as 4x4 16x16 C-frags.
// ---------------------------------------------------------------------------
template <int RELU, int ELU>
__device__ __forceinline__ void ln_epilogue(
    f32x4 (&acc)[4][4], const float* __restrict__ bias,
    const float* __restrict__ g, const float* __restrict__ b,
    unsigned short* __restrict__ out,
    int rowBase, int wr, int wc, int lg, int l15, int wh,
    float* rsum, float* rsq, int N) {
    float bv[4], gv[4], bbv[4];
    #pragma unroll
    for (int cb = 0; cb < 4; ++cb) {
        int col = wc + cb * 16 + l15;
        bv[cb] = bias[col];
        gv[cb] = g[col];
        bbv[cb] = b[col];
    }
    float ps[4][4], pq[4][4];
    #pragma unroll
    for (int rb = 0; rb < 4; ++rb)
        #pragma unroll
        for (int q = 0; q < 4; ++q) {
            float s = 0.f, sq = 0.f;
            #pragma unroll
            for (int cb = 0; cb < 4; ++cb) {
                float v = acc[rb][cb][q] + bv[cb];
                if (RELU) v = fmaxf(v, 0.f);
                s += v;
                sq += v * v;
            }
            ps[rb][q] = s;
            pq[rb][q] = sq;
        }
    #pragma unroll
    for (int m = 1; m < 16; m <<= 1) {
        #pragma unroll
        for (int rb = 0; rb < 4; ++rb)
            #pragma unroll
            for (int q = 0; q < 4; ++q) {
                ps[rb][q] += __shfl_xor(ps[rb][q], m, 64);
                pq[rb][q] += __shfl_xor(pq[rb][q], m, 64);
            }
    }
    if (l15 == 0) {
        #pragma unroll
        for (int rb = 0; rb < 4; ++rb)
            #pragma unroll
            for (int q = 0; q < 4; ++q) {
                int row = wr + rb * 16 + lg * 4 + q;
                rsum[wh * 128 + row] = ps[rb][q];
                rsq[wh * 128 + row] = pq[rb][q];
            }
    }
    __syncthreads();
    #pragma unroll
    for (int rb = 0; rb < 4; ++rb)
        #pragma unroll
        for (int q = 0; q < 4; ++q) {
            int row = wr + rb * 16 + lg * 4 + q;
            float st = rsum[row] + rsum[128 + row];
            float sqt = rsq[row] + rsq[128 + row];
            float mu = st * (1.f / 128.f);
            float var = sqt * (1.f / 128.f) - mu * mu;
            float rs = rsqrtf(var + 1e-5f);
            int grow = rowBase + row;
            if (grow < N) {
                #pragma unroll
                for (int cb = 0; cb < 4; ++cb) {
                    float v = acc[rb][cb][q] + bv[cb];
                    if (RELU) v = fmaxf(v, 0.f);
                    float y = (v - mu) * rs * gv[cb] + bbv[cb];
                    if (ELU) y = y > 0.f ? y : expm1f(y);
                    out[(size_t)grow * D_EMB + wc + cb * 16 + l15] = f2bf(y);
                }
            }
        }
}

// ---------------------------------------------------------------------------
// Encoder GEMM: hb = relu(xb @ W_in + b_in), K=64, bf16 MFMA
// ---------------------------------------------------------------------------
__global__ __launch_bounds__(256) void enc_gemm_k(
    const unsigned short* __restrict__ Abf, const unsigned short* __restrict__ Wf,
    const float* __restrict__ bias, unsigned short* __restrict__ C, int N) {
    __shared__ unsigned short As[4 * 128 * 8];
    const int tid = threadIdx.x;
    const int wid = tid >> 6, lane = tid & 63;
    const int l15 = lane & 15, lg = lane >> 4;
    const int rowBase = blockIdx.x * 128;
    const int wr = (wid >> 1) * 64, wc = (wid & 1) * 64;
    f32x4 zero = {0.f, 0.f, 0.f, 0.f};
    f32x4 acc[4][4];
    #pragma unroll
    for (int i = 0; i < 4; ++i)
        #pragma unroll
        for (int j = 0; j < 4; ++j) acc[i][j] = zero;
    const int r = tid >> 1, hp = tid & 1;
    const int arow = min(rowBase + r, N - 1);

    for (int k0 = 0; k0 < D_IN; k0 += 32) {
        bf16x8 bfr[4];
        const int G = (k0 >> 3) + lg;
        #pragma unroll
        for (int cb = 0; cb < 4; ++cb)
            bfr[cb] = *(const bf16x8*)&Wf[(((size_t)G * 128) + wc + cb * 16 + l15) * 8];
        __syncthreads();
        #pragma unroll
        for (int g2 = 0; g2 < 2; ++g2) {
            int gg = hp * 2 + g2;
            int k = k0 + gg * 8;
            uint4 w = *(const uint4*)(Abf + (size_t)arow * D_IN + k);
            *(uint4*)&As[(((size_t)gg * 128) + r) * 8] = w;
        }
        __syncthreads();
        #pragma unroll
        for (int rb = 0; rb < 4; ++rb) {
            bf16x8 afr = *(const bf16x8*)&As[(((size_t)lg * 128) + wr + rb * 16 + l15) * 8];
            #pragma unroll
            for (int cb = 0; cb < 4; ++cb)
                acc[rb][cb] = __builtin_amdgcn_mfma_f32_16x16x32_bf16(afr, bfr[cb], acc[rb][cb], 0, 0, 0);
        }
    }
    #pragma unroll
    for (int cb = 0; cb < 4; ++cb) {
        int col = wc + cb * 16 + l15;
        float bvv = bias[col];
        #pragma unroll
        for (int rb = 0; rb < 4; ++rb)
            #pragma unroll
            for (int q = 0; q < 4; ++q) {
                int row = rowBase + wr + rb * 16 + lg * 4 + q;
                if (row < N) C[(size_t)row * D_EMB + col] = f2bf(fmaxf(acc[rb][cb][q] + bvv, 0.f));
            }
    }
}

// ---------------------------------------------------------------------------
// Fused GIN layer WITH in-kernel h-aggregation.
// Phase A (gather): 4 waves x 32 rows; full-row 256B gathers of h neighbors
//   (identical arithmetic/order to round-6 agg128b), z_h = es*h + agg packed
//   bf16 into LDS ZT[16][128][8] (GEMM1 A-fragments for k in [64,192)).
// Phase B: GEMM1 (k<64 staged from xb/aggx as before; k>=64 from ZT).
// Phase C: ZT reused as T1 for GEMM2, then LN+ELU epilogue.
// Removes the aggh global round-trip (~100MB/layer) and the agg->gemm kernel
// barrier (gather of one block overlaps MFMA of co-resident blocks).
// ---------------------------------------------------------------------------
__global__ __launch_bounds__(256) void gin_layer_k(
    const unsigned short* __restrict__ xb, const unsigned short* __restrict__ hbi,
    const float* __restrict__ aggx, const float* __restrict__ epsp,
    const int* __restrict__ rp, const int* __restrict__ cs,
    const unsigned short* __restrict__ W1f, const float* __restrict__ b1,
    const unsigned short* __restrict__ W2f, const float* __restrict__ b2,
    const float* __restrict__ lng, const float* __restrict__ lnb,
    unsigned short* __restrict__ hbo, int N) {
    __shared__ unsigned short ZT[16 * 128 * 8];  // 32 KB: z_h frags, then T1 frags
    __shared__ unsigned short As[4 * 128 * 8];   // 8 KB: GEMM1 k<64 staging
    __shared__ float rsum[2 * 128];
    __shared__ float rsq[2 * 128];

    const int tid = threadIdx.x;
    const int wid = tid >> 6, lane = tid & 63;
    const int l15 = lane & 15, lg = lane >> 4;
    const int rowBase = blockIdx.x * 128;
    const int wr = (wid >> 1) * 64, wc = (wid & 1) * 64;
    const int wh = wid & 1;
    const float es = 1.0f + epsp[0];

    // ---- Phase A: gather h-neighbor sums for this block's 128 rows ----
    {
        const unsigned int* h2 = (const unsigned int*)hbi;
        const int zg = lane >> 2;              // ZT k-group for col pair (2*lane)
        const int ze = (2 * lane) & 7;
        for (int i = 0; i < 32; ++i) {
            int row = wid * 32 + i;
            int n = rowBase + row;
            float sx = 0.f, sy = 0.f;
            if (n < N) {
                int bg = rp[n], en = rp[n + 1];
                int j = bg;
                for (; j + 3 < en; j += 4) {
                    unsigned int v0 = h2[(size_t)cs[j] * 64 + lane];
                    unsigned int v1 = h2[(size_t)cs[j + 1] * 64 + lane];
                    unsigned int v2 = h2[(size_t)cs[j + 2] * 64 + lane];
                    unsigned int v3 = h2[(size_t)cs[j + 3] * 64 + lane];
                    sx += bflo(v0) + bflo(v1) + bflo(v2) + bflo(v3);
                    sy += bfhi(v0) + bfhi(v1) + bfhi(v2) + bfhi(v3);
                }
                for (; j < en; ++j) {
                    unsigned int v = h2[(size_t)cs[j] * 64 + lane];
                    sx += bflo(v);
                    sy += bfhi(v);
                }
                unsigned int hv = h2[(size_t)n * 64 + lane];
                sx = fmaf(es, bflo(hv), sx);
                sy = fmaf(es, bfhi(hv), sy);
            }
            *(unsigned int*)&ZT[(((size_t)zg * 128) + row) * 8 + ze] = pk2(f2bf(sx), f2bf(sy));
        }
    }
    __syncthreads();

    f32x4 zero = {0.f, 0.f, 0.f, 0.f};
    f32x4 acc[4][4];
    #pragma unroll
    for (int i = 0; i < 4; ++i)
        #pragma unroll
        for (int j = 0; j < 4; ++j) acc[i][j] = zero;

    const int r = tid >> 1, hp = tid & 1;
    const int arow = min(rowBase + r, N - 1);

    // ---- Phase B: GEMM1. k<64: staged x-part; k>=64: straight from ZT ----
    for (int k0 = 0; k0 < D_IN; k0 += 32) {
        bf16x8 bfr[4];
        const int G = (k0 >> 3) + lg;
        #pragma unroll
        for (int cb = 0; cb < 4; ++cb)
            bfr[cb] = *(const bf16x8*)&W1f[(((size_t)G * 128) + wc + cb * 16 + l15) * 8];
        __syncthreads();
        #pragma unroll
        for (int g2 = 0; g2 < 2; ++g2) {
            int gg = hp * 2 + g2;
            int k = k0 + gg * 8;
            uint4 xv = *(const uint4*)(xb + (size_t)arow * D_IN + k);
            const float* gp = aggx + (size_t)arow * D_IN + k;
            float4 g0 = *(const float4*)gp, g1 = *(const float4*)(gp + 4);
            unsigned short o[8];
            o[0] = f2bf(fmaf(es, bflo(xv.x), g0.x));
            o[1] = f2bf(fmaf(es, bfhi(xv.x), g0.y));
            o[2] = f2bf(fmaf(es, bflo(xv.y), g0.z));
            o[3] = f2bf(fmaf(es, bfhi(xv.y), g0.w));
            o[4] = f2bf(fmaf(es, bflo(xv.z), g1.x));
            o[5] = f2bf(fmaf(es, bfhi(xv.z), g1.y));
            o[6] = f2bf(fmaf(es, bflo(xv.w), g1.z));
            o[7] = f2bf(fmaf(es, bfhi(xv.w), g1.w));
            *(uint4*)&As[(((size_t)gg * 128) + r) * 8] =
                make_uint4(pk2(o[0], o[1]), pk2(o[2], o[3]), pk2(o[4], o[5]), pk2(o[6], o[7]));
        }
        __syncthreads();
        #pragma unroll
        for (int rb = 0; rb < 4; ++rb) {
            bf16x8 afr = *(const bf16x8*)&As[(((size_t)lg * 128) + wr + rb * 16 + l15) * 8];
            #pragma unroll
            for (int cb = 0; cb < 4; ++cb)
                acc[rb][cb] = __builtin_amdgcn_mfma_f32_16x16x32_bf16(afr, bfr[cb], acc[rb][cb], 0, 0, 0);
        }
    }
    for (int k0 = D_IN; k0 < GI; k0 += 32) {
        bf16x8 bfr[4];
        const int G = (k0 >> 3) + lg;
        const int ZG = ((k0 - D_IN) >> 3) + lg;
        #pragma unroll
        for (int cb = 0; cb < 4; ++cb)
            bfr[cb] = *(const bf16x8*)&W1f[(((size_t)G * 128) + wc + cb * 16 + l15) * 8];
        #pragma unroll
        for (int rb = 0; rb < 4; ++rb) {
            bf16x8 afr = *(const bf16x8*)&ZT[(((size_t)ZG * 128) + wr + rb * 16 + l15) * 8];
            #pragma unroll
            for (int cb = 0; cb < 4; ++cb)
                acc[rb][cb] = __builtin_amdgcn_mfma_f32_16x16x32_bf16(afr, bfr[cb], acc[rb][cb], 0, 0, 0);
        }
    }

    // ---- Phase C: t1 -> ZT (reuse as T1), GEMM2, LN+ELU ----
    __syncthreads();  // all ZT reads done before overwrite
    #pragma unroll
    for (int cb = 0; cb < 4; ++cb) {
        int col = wc + cb * 16 + l15;
        float bvv = b1[col];
        #pragma unroll
        for (int rb = 0; rb < 4; ++rb)
            #pragma unroll
            for (int q = 0; q < 4; ++q) {
                int row = wr + rb * 16 + lg * 4 + q;
                float v = fmaxf(acc[rb][cb][q] + bvv, 0.f);
                ZT[(((size_t)(col >> 3) * 128) + row) * 8 + (col & 7)] = f2bf(v);
            }
    }
    __syncthreads();

    f32x4 acc2[4][4];
    #pragma unroll
    for (int i = 0; i < 4; ++i)
        #pragma unroll
        for (int j = 0; j < 4; ++j) acc2[i][j] = zero;
    for (int k0 = 0; k0 < D_EMB; k0 += 32) {
        bf16x8 bfr[4];
        const int G = (k0 >> 3) + lg;
        #pragma unroll
        for (int cb = 0; cb < 4; ++cb)
            bfr[cb] = *(const bf16x8*)&W2f[(((size_t)G * 128) + wc + cb * 16 + l15) * 8];
        #pragma unroll
        for (int rb = 0; rb < 4; ++rb) {
            bf16x8 afr = *(const bf16x8*)&ZT[(((size_t)G * 128) + wr + rb * 16 + l15) * 8];
            #pragma unroll
            for (int cb = 0; cb < 4; ++cb)
                acc2[rb][cb] = __builtin_amdgcn_mfma_f32_16x16x32_bf16(afr, bfr[cb], acc2[rb][cb], 0, 0, 0);
        }
    }

    ln_epilogue<0, 1>(acc2, b2, lng, lnb, hbo, rowBase, wr, wc, lg, l15, wh, rsum, rsq, N);
}

// ---------------------------------------------------------------------------
// Fused FC + LN
// ---------------------------------------------------------------------------
template <int RELU, int ELU>
__global__ __launch_bounds__(256) void fc_ln_k(
    const unsigned short* __restrict__ Abf, const unsigned short* __restrict__ Wf,
    const float* __restrict__ bias, const float* __restrict__ g, const float* __restrict__ b,
    unsigned short* __restrict__ out, int N) {
    __shared__ unsigned short As[4 * 128 * 8];
    __shared__ float rsum[2 * 128];
    __shared__ float rsq[2 * 128];
    const int tid = threadIdx.x;
    const int wid = tid >> 6, lane = tid & 63;
    const int l15 = lane & 15, lg = lane >> 4;
    const int rowBase = blockIdx.x * 128;
    const int wr = (wid >> 1) * 64, wc = (wid & 1) * 64;
    const int wh = wid & 1;
    f32x4 zero = {0.f, 0.f, 0.f, 0.f};
    f32x4 acc[4][4];
    #pragma unroll
    for (int i = 0; i < 4; ++i)
        #pragma unroll
        for (int j = 0; j < 4; ++j) acc[i][j] = zero;
    const int r = tid >> 1, hp = tid & 1;
    const int arow = min(rowBase + r, N - 1);

    for (int k0 = 0; k0 < D_EMB; k0 += 32) {
        bf16x8 bfr[4];
        const int G = (k0 >> 3) + lg;
        #pragma unroll
        for (int cb = 0; cb < 4; ++cb)
            bfr[cb] = *(const bf16x8*)&Wf[(((size_t)G * 128) + wc + cb * 16 + l15) * 8];
        __syncthreads();
        #pragma unroll
        for (int g2 = 0; g2 < 2; ++g2) {
            int gg = hp * 2 + g2;
            int k = k0 + gg * 8;
            uint4 w = *(const uint4*)(Abf + (size_t)arow * D_EMB + k);
            *(uint4*)&As[(((size_t)gg * 128) + r) * 8] = w;
        }
        __syncthreads();
        #pragma unroll
        for (int rb = 0; rb < 4; ++rb) {
            bf16x8 afr = *(const bf16x8*)&As[(((size_t)lg * 128) + wr + rb * 16 + l15) * 8];
            #pragma unroll
            for (int cb = 0; cb < 4; ++cb)
                acc[rb][cb] = __builtin_amdgcn_mfma_f32_16x16x32_bf16(afr, bfr[cb], acc[rb][cb], 0, 0, 0);
        }
    }
    ln_epilogue<RELU, ELU>(acc, bias, g, b, out, rowBase, wr, wc, lg, l15, wh, rsum, rsq, N);
}

// ---------------------------------------------------------------------------
// Graph segment bounds, then 8-way-split mean pool
// ---------------------------------------------------------------------------
__global__ __launch_bounds__(256) void bounds_k(const int* __restrict__ batch, int* __restrict__ bounds,
                                                int N, int B) {
    int i = blockIdx.x * 256 + threadIdx.x;
    if (i <= B) {
        int lo = 0, hi = N;
        while (lo < hi) { int m = (lo + hi) >> 1; if (batch[m] < i) lo = m + 1; else hi = m; }
        bounds[i] = lo;
    }
}

__global__ __launch_bounds__(128) void pool_part_k(const unsigned short* __restrict__ ge,
                                                   const int* __restrict__ bounds,
                                                   float* __restrict__ gemb) {
    int b = blockIdx.x >> 3;
    int s = blockIdx.x & 7;
    int start = bounds[b], end = bounds[b + 1];
    int len = end - start;
    int c0 = start + (int)(((long long)len * s) >> 3);
    int c1 = start + (int)(((long long)len * (s + 1)) >> 3);
    if (c1 <= c0) return;
    int col = threadIdx.x;
    float sum = 0.f;
    for (int n = c0; n < c1; ++n)
        sum += __uint_as_float((unsigned int)ge[(size_t)n * D_EMB + col] << 16);
    atomicAdd(&gemb[(size_t)b * D_EMB + col], sum);
}

// ---------------------------------------------------------------------------
// Node decoder: per-thread MLP [x fp32 | node_emb bf16](192) -> 32 -> 8 -> 1
// ---------------------------------------------------------------------------
__global__ __launch_bounds__(256) void node_dec_k(
    const float* __restrict__ x, const unsigned short* __restrict__ ne,
    const float* __restrict__ W1, const float* __restrict__ b1,
    const float* __restrict__ W2, const float* __restrict__ b2,
    const float* __restrict__ W3, const float* __restrict__ b3,
    float* __restrict__ out, int N) {
    __shared__ float W1s[GI * H1];
    __shared__ float W2s[H1 * H2];
    __shared__ float W3s[H2];
    __shared__ float b1s[H1], b2s[H2];
    for (int i = threadIdx.x; i < GI * H1; i += 256) W1s[i] = W1[i];
    if (threadIdx.x < H1 * H2) W2s[threadIdx.x] = W2[threadIdx.x];
    if (threadIdx.x < H2) { W3s[threadIdx.x] = W3[threadIdx.x]; b2s[threadIdx.x] = b2[threadIdx.x]; }
    if (threadIdx.x < H1) b1s[threadIdx.x] = b1[threadIdx.x];
    __syncthreads();
    int n = blockIdx.x * 256 + threadIdx.x;
    if (n >= N) return;
    float acc[H1];
    #pragma unroll
    for (int j = 0; j < H1; ++j) acc[j] = b1s[j];
    const float4* xr = (const float4*)(x + (size_t)n * D_IN);
    #pragma unroll 4
    for (int q = 0; q < D_IN / 4; ++q) {
        float4 v = xr[q];
        int k = q * 4;
        #pragma unroll
        for (int j = 0; j < H1; ++j) acc[j] = fmaf(v.x, W1s[(k + 0) * H1 + j], acc[j]);
        #pragma unroll
        for (int j = 0; j < H1; ++j) acc[j] = fmaf(v.y, W1s[(k + 1) * H1 + j], acc[j]);
        #pragma unroll
        for (int j = 0; j < H1; ++j) acc[j] = fmaf(v.z, W1s[(k + 2) * H1 + j], acc[j]);
        #pragma unroll
        for (int j = 0; j < H1; ++j) acc[j] = fmaf(v.w, W1s[(k + 3) * H1 + j], acc[j]);
    }
    const uint4* nr = (const uint4*)(ne + (size_t)n * D_EMB);
    #pragma unroll 4
    for (int q = 0; q < 16; ++q) {
        uint4 v = nr[q];
        float f[8] = {bflo(v.x), bfhi(v.x), bflo(v.y), bfhi(v.y),
                      bflo(v.z), bfhi(v.z), bflo(v.w), bfhi(v.w)};
        int k = D_IN + q * 8;
        #pragma unroll
        for (int e = 0; e < 8; ++e) {
            #pragma unroll
            for (int j = 0; j < H1; ++j) acc[j] = fmaf(f[e], W1s[(k + e) * H1 + j], acc[j]);
        }
    }
    #pragma unroll
    for (int j = 0; j < H1; ++j) acc[j] = fmaxf(acc[j], 0.f);
    float a2[H2];
    #pragma unroll
    for (int m = 0; m < H2; ++m) a2[m] = b2s[m];
    #pragma unroll
    for (int j = 0; j < H1; ++j)
        #pragma unroll
        for (int m = 0; m < H2; ++m) a2[m] = fmaf(acc[j], W2s[j * H2 + m], a2[m]);
    float o = b3[0];
    #pragma unroll
    for (int m = 0; m < H2; ++m) o = fmaf(fmaxf(a2[m], 0.f), W3s[m], o);
    out[n] = o;
}

// ---------------------------------------------------------------------------
// Graph decoder: mean-divide fused (reads summed gemb + bounds)
// ---------------------------------------------------------------------------
__global__ __launch_bounds__(256) void graph_dec_k(
    const float* __restrict__ gemb, const int* __restrict__ bounds,
    const float* __restrict__ W1, const float* __restrict__ b1,
    const float* __restrict__ W2, const float* __restrict__ b2,
    const float* __restrict__ W3, const float* __restrict__ b3,
    float* __restrict__ out, int B) {
    __shared__ float W1s[D_EMB * H1];
    __shared__ float W2s[H1 * H2];
    __shared__ float W3s[H2];
    __shared__ float b1s[H1], b2s[H2];
    for (int i = threadIdx.x; i < D_EMB * H1; i += 256) W1s[i] = W1[i];
    if (threadIdx.x < H1 * H2) W2s[threadIdx.x] = W2[threadIdx.x];
    if (threadIdx.x < H2) { W3s[threadIdx.x] = W3[threadIdx.x]; b2s[threadIdx.x] = b2[threadIdx.x]; }
    if (threadIdx.x < H1) b1s[threadIdx.x] = b1[threadIdx.x];
    __syncthreads();
    int gidx = threadIdx.x;
    if (gidx >= B) return;
    int len = bounds[gidx + 1] - bounds[gidx];
    float inv = 1.f / fmaxf((float)len, 1.f);
    float acc[H1];
    #pragma unroll
    for (int j = 0; j < H1; ++j) acc[j] = b1s[j];
    const float4* gr = (const float4*)(gemb + (size_t)gidx * D_EMB);
    for (int q = 0; q < D_EMB / 4; ++q) {
        float4 v = gr[q];
        v.x *= inv; v.y *= inv; v.z *= inv; v.w *= inv;
        int k = q * 4;
        #pragma unroll
        for (int j = 0; j < H1; ++j) acc[j] = fmaf(v.x, W1s[(k + 0) * H1 + j], acc[j]);
        #pragma unroll
        for (int j = 0; j < H1; ++j) acc[j] = fmaf(v.y, W1s[(k + 1) * H1 + j], acc[j]);
        #pragma unroll
        for (int j = 0; j < H1; ++j) acc[j] = fmaf(v.z, W1s[(k + 2) * H1 + j], acc[j]);
        #pragma unroll
        for (int j = 0; j < H1; ++j) acc[j] = fmaf(v.w, W1s[(k + 3) * H1 + j], acc[j]);
    }
    #pragma unroll
    for (int j = 0; j < H1; ++j) acc[j] = fmaxf(acc[j], 0.f);
    float a2[H2];
    #pragma unroll
    for (int m = 0; m < H2; ++m) a2[m] = b2s[m];
    #pragma unroll
    for (int j = 0; j < H1; ++j)
        #pragma unroll
        for (int m = 0; m < H2; ++m) a2[m] = fmaf(acc[j], W2s[j * H2 + m], a2[m]);
    float o = b3[0];
    #pragma unroll
    for (int m = 0; m < H2; ++m) o = fmaf(fmaxf(a2[m], 0.f), W3s[m], o);
    out[gidx] = o;
}

// ---------------------------------------------------------------------------
extern "C" void kernel_launch(void* const* d_in, const int* in_sizes, int n_in,
                              void* d_out, int out_size, void* d_ws, size_t ws_size,
                              hipStream_t stream) {
    const float* x       = (const float*)d_in[0];
    const int*   ei      = (const int*)d_in[1];
    const int*   batch   = (const int*)d_in[2];
    const float* W_in    = (const float*)d_in[3];
    const float* b_in    = (const float*)d_in[4];
    const float* eps     = (const float*)d_in[5];
    const float* mlp_W1  = (const float*)d_in[6];
    const float* mlp_b1  = (const float*)d_in[7];
    const float* mlp_W2  = (const float*)d_in[8];
    const float* mlp_b2  = (const float*)d_in[9];
    const float* ln_g    = (const float*)d_in[10];
    const float* ln_b    = (const float*)d_in[11];
    const float* out_W   = (const float*)d_in[12];
    const float* out_b   = (const float*)d_in[13];
    const float* lnf_g   = (const float*)d_in[14];
    const float* lnf_b   = (const float*)d_in[15];
    const float* graph_W = (const float*)d_in[16];
    const float* graph_b = (const float*)d_in[17];
    const float* gln_g   = (const float*)d_in[18];
    const float* gln_b   = (const float*)d_in[19];
    const float* dW1     = (const float*)d_in[20];
    const float* db1     = (const float*)d_in[21];
    const float* dW2     = (const float*)d_in[22];
    const float* db2     = (const float*)d_in[23];
    const float* dW3     = (const float*)d_in[24];
    const float* db3     = (const float*)d_in[25];
    const float* gW1     = (const float*)d_in[26];
    const float* gb1     = (const float*)d_in[27];
    const float* gW2     = (const float*)d_in[28];
    const float* gb2     = (const float*)d_in[29];
    const float* gW3     = (const float*)d_in[30];
    const float* gb3     = (const float*)d_in[31];
    float* out = (float*)d_out;

    const int N = in_sizes[0] / D_IN;
    const int E = in_sizes[1] / 2;
    const int B = out_size - N;
    const int N8 = (N + 7) / 8;

    const int* esrc = ei;
    const int* edst = ei + E;

    // workspace layout
    size_t off = 0;
    auto alloc = [&](size_t bytes) { size_t o = off; off += (bytes + 255) & ~(size_t)255; return o; };
    char* ws = (char*)d_ws;
    unsigned short* xb  = (unsigned short*)(ws + alloc((size_t)N * D_IN * 2));
    unsigned short* hb0 = (unsigned short*)(ws + alloc((size_t)N * D_EMB * 2));
    unsigned short* hb1 = (unsigned short*)(ws + alloc((size_t)N * D_EMB * 2));
    float* aggx = (float*)(ws + alloc((size_t)N * D_IN * 4));
    float* gemb = (float*)(ws + alloc((size_t)B * D_EMB * 4));
    unsigned short* wfpool = (unsigned short*)(ws + alloc((size_t)163840 * 2));
    int* row_ptr = (int*)(ws + alloc((size_t)(N + 1) * 4));
    int* cnt     = (int*)(ws + alloc((size_t)N * 4));
    int* bsum    = (int*)(ws + alloc(512 * 4));
    int* bounds  = (int*)(ws + alloc((size_t)(B + 1) * 4));
    int* csr     = (int*)(ws + alloc((size_t)E * 4));
    (void)ws_size;

    unsigned short* wf_in    = wfpool;
    unsigned short* wf_w1    = wf_in + (size_t)64 * 128;
    unsigned short* wf_w2    = wf_w1 + (size_t)3 * 192 * 128;
    unsigned short* wf_graph = wf_w2 + (size_t)3 * 128 * 128;
    unsigned short* wf_out   = wf_graph + (size_t)128 * 128;

    unsigned short* zb  = hb0;                    // graph-branch LN out (hb0 free after layer 2)
    unsigned short* neb = (unsigned short*)aggx;  // node-branch LN out (aggx free after last layer)

    const int NB = (N + 255) / 256;
    const int gridEP = 8 * ((E + 1023) / 1024);
    const int gridG = (N + 127) / 128;

    // ---- CSR build (XCD-partitioned hist/scatter) ----
    hipMemsetAsync(cnt, 0, (size_t)N * 4, stream);
    hist_part_k<<<gridEP, 256, 0, stream>>>(edst, cnt, E, N8);
    scan1_k<<<NB, 256, 0, stream>>>(cnt, row_ptr, bsum, N);
    scan2_k<<<1, 512, 0, stream>>>(bsum, NB);
    scan3_k<<<(N + 256) / 256, 256, 0, stream>>>(row_ptr, bsum, cnt, N, E);
    scatter_part_k<<<gridEP, 256, 0, stream>>>(esrc, edst, cnt, csr, E, N8);

    // ---- prep: x -> bf16, weights -> fragment pool, graph bounds, gemb zero ----
    xcvt_k<<<(N * D_IN / 4 + 255) / 256, 256, 0, stream>>>(x, xb, N * D_IN / 4);
    wfrag_all_k<<<640, 256, 0, stream>>>(W_in, mlp_W1, mlp_W2, graph_W, out_W,
                                         wf_in, wf_w1, wf_w2, wf_graph, wf_out);
    bounds_k<<<(B + 256) / 256, 256, 0, stream>>>(batch, bounds, N, B);
    hipMemsetAsync(gemb, 0, (size_t)B * D_EMB * 4, stream);

    // ---- x aggregation (layer-invariant, full-row gather) ----
    agg64b_k<<<(N + 7) / 8, 256, 0, stream>>>(xb, row_ptr, csr, aggx, N);

    // ---- encoder ----
    enc_gemm_k<<<gridG, 256, 0, stream>>>(xb, wf_in, b_in, hb0, N);

    // ---- GIN layers (gather fused into the layer kernel) ----
    unsigned short* hin = hb0;
    unsigned short* hout = hb1;
    for (int l = 0; l < 3; ++l) {
        gin_layer_k<<<gridG, 256, 0, stream>>>(xb, hin, aggx, eps + l, row_ptr, csr,
                                               wf_w1 + (size_t)l * 192 * 128, mlp_b1 + (size_t)l * D_EMB,
                                               wf_w2 + (size_t)l * 128 * 128, mlp_b2 + (size_t)l * D_EMB,
                                               ln_g + (size_t)l * D_EMB, ln_b + (size_t)l * D_EMB,
                                               hout, N);
        unsigned short* t = hin; hin = hout; hout = t;
    }
    // final h in hin (= hb1)

    // ---- graph branch ----
    fc_ln_k<1, 0><<<gridG, 256, 0, stream>>>(hin, wf_graph, graph_b, gln_g, gln_b, zb, N);
    pool_part_k<<<B * 8, 128, 0, stream>>>(zb, bounds, gemb);

    // ---- node branch ----
    fc_ln_k<1, 0><<<gridG, 256, 0, stream>>>(hin, wf_out, out_b, lnf_g, lnf_b, neb, N);

    // ---- decoders ----
    node_dec_k<<<(N + 255) / 256, 256, 0, stream>>>(x, neb, dW1, db1, dW2, db2, dW3, db3, out, N);
    graph_dec_k<<<1, 256, 0, stream>>>(gemb, bounds, gW1, gb1, gW2, gb2, gW3, gb3, out + N, B);
}

// Round 9
// 826.787 us; speedup vs baseline: 1.5822x; 1.5822x over previous
//
#include <hip/hip_runtime.h>
#include <hip/hip_bf16.h>

#define D_IN 64
#define D_EMB 128
#define GI 192           // D_IN + D_EMB
#define H1 32
#define H2 8

typedef __attribute__((ext_vector_type(8))) short bf16x8;
typedef __attribute__((ext_vector_type(4))) float f32x4;

__device__ __forceinline__ unsigned short f2bf(float f) {
    unsigned int u = __float_as_uint(f);
    return (unsigned short)((u + 0x7fffu + ((u >> 16) & 1u)) >> 16);
}
__device__ __forceinline__ float bflo(unsigned int u) { return __uint_as_float(u << 16); }
__device__ __forceinline__ float bfhi(unsigned int u) { return __uint_as_float(u & 0xffff0000u); }
__device__ __forceinline__ unsigned int pk2(unsigned short a, unsigned short b) {
    return (unsigned int)a | ((unsigned int)b << 16);
}

// ---------------------------------------------------------------------------
// CSR build, XCD-partitioned (round-3 notes: merges partial-line writes in L2)
// ---------------------------------------------------------------------------
__global__ __launch_bounds__(256) void hist_part_k(const int* __restrict__ dst, int* __restrict__ cnt,
                                                   int E, int N8) {
    int p = blockIdx.x & 7;
    int base = (blockIdx.x >> 3) * 1024;
    int lo = p * N8, hi = lo + N8;
    #pragma unroll
    for (int t = 0; t < 4; ++t) {
        int e = base + t * 256 + threadIdx.x;
        if (e < E) {
            int d = dst[e];
            if (d >= lo && d < hi) atomicAdd(&cnt[d], 1);
        }
    }
}

__global__ __launch_bounds__(256) void scan1_k(const int* __restrict__ cnt, int* __restrict__ loc,
                                               int* __restrict__ bsum, int N) {
    __shared__ int s[256];
    int tid = threadIdx.x;
    int i = blockIdx.x * 256 + tid;
    int v = (i < N) ? cnt[i] : 0;
    s[tid] = v;
    __syncthreads();
    #pragma unroll
    for (int off = 1; off < 256; off <<= 1) {
        int u = (tid >= off) ? s[tid - off] : 0;
        __syncthreads();
        s[tid] += u;
        __syncthreads();
    }
    int incl = s[tid];
    if (i < N) loc[i] = incl - v;
    if (tid == 255) bsum[blockIdx.x] = incl;
}

__global__ __launch_bounds__(512) void scan2_k(int* __restrict__ bsum, int NB) {
    __shared__ int s[512];
    int tid = threadIdx.x;
    int v = (tid < NB) ? bsum[tid] : 0;
    s[tid] = v;
    __syncthreads();
    #pragma unroll
    for (int off = 1; off < 512; off <<= 1) {
        int u = (tid >= off) ? s[tid - off] : 0;
        __syncthreads();
        s[tid] += u;
        __syncthreads();
    }
    if (tid < NB) bsum[tid] = s[tid] - v;
}

__global__ __launch_bounds__(256) void scan3_k(int* __restrict__ rp, const int* __restrict__ bsum,
                                               int* __restrict__ cursor, int N, int E) {
    int i = blockIdx.x * 256 + threadIdx.x;
    if (i < N) {
        int r = rp[i] + bsum[i >> 8];
        rp[i] = r;
        cursor[i] = r;
    } else if (i == N) {
        rp[N] = E;
    }
}

__global__ __launch_bounds__(256) void scatter_part_k(const int* __restrict__ src, const int* __restrict__ dst,
                                                      int* __restrict__ cursor, int* __restrict__ csr,
                                                      int E, int N8) {
    int p = blockIdx.x & 7;
    int base = (blockIdx.x >> 3) * 1024;
    int lo = p * N8, hi = lo + N8;
    #pragma unroll
    for (int t = 0; t < 4; ++t) {
        int e = base + t * 256 + threadIdx.x;
        if (e < E) {
            int d = dst[e];
            if (d >= lo && d < hi) {
                int s = src[e];
                int pos = atomicAdd(&cursor[d], 1);
                csr[pos] = s;
            }
        }
    }
}

// ---------------------------------------------------------------------------
// Conversions / weight fragment prep
// ---------------------------------------------------------------------------
__global__ __launch_bounds__(256) void xcvt_k(const float* __restrict__ x, unsigned short* __restrict__ xb,
                                              int total4) {
    int i = blockIdx.x * 256 + threadIdx.x;
    if (i < total4) {
        float4 v = ((const float4*)x)[i];
        ((uint2*)xb)[i] = make_uint2(pk2(f2bf(v.x), f2bf(v.y)), pk2(f2bf(v.z), f2bf(v.w)));
    }
}

__global__ __launch_bounds__(256) void wfrag_all_k(
    const float* __restrict__ W_in, const float* __restrict__ mlp_W1, const float* __restrict__ mlp_W2,
    const float* __restrict__ graph_W, const float* __restrict__ out_W,
    unsigned short* __restrict__ wf_in, unsigned short* __restrict__ wf_w1,
    unsigned short* __restrict__ wf_w2, unsigned short* __restrict__ wf_graph,
    unsigned short* __restrict__ wf_out) {
    int idx = blockIdx.x * 256 + threadIdx.x;
    const float* src;
    unsigned short* dst;
    int local;
    if (idx < 8192) { src = W_in; dst = wf_in; local = idx; }
    else if (idx < 81920) { int t = idx - 8192; int l = t / 24576; local = t - l * 24576;
                            src = mlp_W1 + (size_t)l * 24576; dst = wf_w1 + (size_t)l * 24576; }
    else if (idx < 131072) { int t = idx - 81920; int l = t / 16384; local = t - l * 16384;
                             src = mlp_W2 + (size_t)l * 16384; dst = wf_w2 + (size_t)l * 16384; }
    else if (idx < 147456) { local = idx - 131072; src = graph_W; dst = wf_graph; }
    else { local = idx - 147456; src = out_W; dst = wf_out; }
    int k = local >> 7, c = local & 127;
    dst[(((size_t)(k >> 3) * 128) + c) * 8 + (k & 7)] = f2bf(src[local]);
}

// ---------------------------------------------------------------------------
// Aggregation over bf16 node tables (fp32 accumulate), 8 loads in flight
// (MLP-bound gather: deeper pipeline per wave; round-6 had 4)
// ---------------------------------------------------------------------------
__global__ __launch_bounds__(256) void agg64b_k(const unsigned short* __restrict__ xb,
                                                const int* __restrict__ rp, const int* __restrict__ cs,
                                                float* __restrict__ out, int N) {
    int n = blockIdx.x * 8 + (threadIdx.x >> 5);
    int lane = threadIdx.x & 31;
    if (n >= N) return;
    int bg = rp[n], e = rp[n + 1];
    const unsigned int* x2 = (const unsigned int*)xb;
    float sx = 0.f, sy = 0.f;
    int j = bg;
    for (; j + 7 < e; j += 8) {
        int i0 = cs[j], i1 = cs[j + 1], i2 = cs[j + 2], i3 = cs[j + 3];
        int i4 = cs[j + 4], i5 = cs[j + 5], i6 = cs[j + 6], i7 = cs[j + 7];
        unsigned int v0 = x2[(size_t)i0 * 32 + lane];
        unsigned int v1 = x2[(size_t)i1 * 32 + lane];
        unsigned int v2 = x2[(size_t)i2 * 32 + lane];
        unsigned int v3 = x2[(size_t)i3 * 32 + lane];
        unsigned int v4 = x2[(size_t)i4 * 32 + lane];
        unsigned int v5 = x2[(size_t)i5 * 32 + lane];
        unsigned int v6 = x2[(size_t)i6 * 32 + lane];
        unsigned int v7 = x2[(size_t)i7 * 32 + lane];
        sx += bflo(v0) + bflo(v1) + bflo(v2) + bflo(v3)
            + bflo(v4) + bflo(v5) + bflo(v6) + bflo(v7);
        sy += bfhi(v0) + bfhi(v1) + bfhi(v2) + bfhi(v3)
            + bfhi(v4) + bfhi(v5) + bfhi(v6) + bfhi(v7);
    }
    for (; j < e; ++j) {
        unsigned int v = x2[(size_t)cs[j] * 32 + lane];
        sx += bflo(v);
        sy += bfhi(v);
    }
    ((float2*)out)[(size_t)n * 32 + lane] = make_float2(sx, sy);
}

__global__ __launch_bounds__(256) void agg128b_k(const unsigned short* __restrict__ hb,
                                                 const int* __restrict__ rp, const int* __restrict__ cs,
                                                 float* __restrict__ out, int N) {
    int w = threadIdx.x >> 6, lane = threadIdx.x & 63;
    int n = blockIdx.x * 4 + w;
    if (n >= N) return;
    int bg = rp[n], e = rp[n + 1];
    const unsigned int* h2 = (const unsigned int*)hb;
    float sx = 0.f, sy = 0.f;
    int j = bg;
    for (; j + 7 < e; j += 8) {
        int i0 = cs[j], i1 = cs[j + 1], i2 = cs[j + 2], i3 = cs[j + 3];
        int i4 = cs[j + 4], i5 = cs[j + 5], i6 = cs[j + 6], i7 = cs[j + 7];
        unsigned int v0 = h2[(size_t)i0 * 64 + lane];
        unsigned int v1 = h2[(size_t)i1 * 64 + lane];
        unsigned int v2 = h2[(size_t)i2 * 64 + lane];
        unsigned int v3 = h2[(size_t)i3 * 64 + lane];
        unsigned int v4 = h2[(size_t)i4 * 64 + lane];
        unsigned int v5 = h2[(size_t)i5 * 64 + lane];
        unsigned int v6 = h2[(size_t)i6 * 64 + lane];
        unsigned int v7 = h2[(size_t)i7 * 64 + lane];
        sx += bflo(v0) + bflo(v1) + bflo(v2) + bflo(v3)
            + bflo(v4) + bflo(v5) + bflo(v6) + bflo(v7);
        sy += bfhi(v0) + bfhi(v1) + bfhi(v2) + bfhi(v3)
            + bfhi(v4) + bfhi(v5) + bfhi(v6) + bfhi(v7);
    }
    for (; j < e; ++j) {
        unsigned int v = h2[(size_t)cs[j] * 64 + lane];
        sx += bflo(v);
        sy += bfhi(v);
    }
    ((float2*)out)[(size_t)n * 64 + lane] = make_float2(sx, sy);
}

// ---------------------------------------------------------------------------
// Cross-wave LayerNorm epilogue for a 128x128 tile held as 4x4 16x16 C-frags.
// ---------------------------------------------------------------------------
template <int RELU, int ELU>
__device__ __forceinline__ void ln_epilogue(
    f32x4 (&acc)[4][4], const float* __restrict__ bias,
    const float* __restrict__ g, const float* __restrict__ b,
    unsigned short* __restrict__ out,
    int rowBase, int wr, int wc, int lg, int l15, int wh,
    float* rsum, float* rsq, int N) {
    float bv[4], gv[4], bbv[4];
    #pragma unroll
    for (int cb = 0; cb < 4; ++cb) {
        int col = wc + cb * 16 + l15;
        bv[cb] = bias[col];
        gv[cb] = g[col];
        bbv[cb] = b[col];
    }
    float ps[4][4], pq[4][4];
    #pragma unroll
    for (int rb = 0; rb < 4; ++rb)
        #pragma unroll
        for (int q = 0; q < 4; ++q) {
            float s = 0.f, sq = 0.f;
            #pragma unroll
            for (int cb = 0; cb < 4; ++cb) {
                float v = acc[rb][cb][q] + bv[cb];
                if (RELU) v = fmaxf(v, 0.f);
                s += v;
                sq += v * v;
            }
            ps[rb][q] = s;
            pq[rb][q] = sq;
        }
    #pragma unroll
    for (int m = 1; m < 16; m <<= 1) {
        #pragma unroll
        for (int rb = 0; rb < 4; ++rb)
            #pragma unroll
            for (int q = 0; q < 4; ++q) {
                ps[rb][q] += __shfl_xor(ps[rb][q], m, 64);
                pq[rb][q] += __shfl_xor(pq[rb][q], m, 64);
            }
    }
    if (l15 == 0) {
        #pragma unroll
        for (int rb = 0; rb < 4; ++rb)
            #pragma unroll
            for (int q = 0; q < 4; ++q) {
                int row = wr + rb * 16 + lg * 4 + q;
                rsum[wh * 128 + row] = ps[rb][q];
                rsq[wh * 128 + row] = pq[rb][q];
            }
    }
    __syncthreads();
    #pragma unroll
    for (int rb = 0; rb < 4; ++rb)
        #pragma unroll
        for (int q = 0; q < 4; ++q) {
            int row = wr + rb * 16 + lg * 4 + q;
            float st = rsum[row] + rsum[128 + row];
            float sqt = rsq[row] + rsq[128 + row];
            float mu = st * (1.f / 128.f);
            float var = sqt * (1.f / 128.f) - mu * mu;
            float rs = rsqrtf(var + 1e-5f);
            int grow = rowBase + row;
            if (grow < N) {
                #pragma unroll
                for (int cb = 0; cb < 4; ++cb) {
                    float v = acc[rb][cb][q] + bv[cb];
                    if (RELU) v = fmaxf(v, 0.f);
                    float y = (v - mu) * rs * gv[cb] + bbv[cb];
                    if (ELU) y = y > 0.f ? y : expm1f(y);
                    out[(size_t)grow * D_EMB + wc + cb * 16 + l15] = f2bf(y);
                }
            }
        }
}

// ---------------------------------------------------------------------------
// Encoder GEMM: hb = relu(xb @ W_in + b_in), K=64, bf16 MFMA
// ---------------------------------------------------------------------------
__global__ __launch_bounds__(256) void enc_gemm_k(
    const unsigned short* __restrict__ Abf, const unsigned short* __restrict__ Wf,
    const float* __restrict__ bias, unsigned short* __restrict__ C, int N) {
    __shared__ unsigned short As[4 * 128 * 8];
    const int tid = threadIdx.x;
    const int wid = tid >> 6, lane = tid & 63;
    const int l15 = lane & 15, lg = lane >> 4;
    const int rowBase = blockIdx.x * 128;
    const int wr = (wid >> 1) * 64, wc = (wid & 1) * 64;
    f32x4 zero = {0.f, 0.f, 0.f, 0.f};
    f32x4 acc[4][4];
    #pragma unroll
    for (int i = 0; i < 4; ++i)
        #pragma unroll
        for (int j = 0; j < 4; ++j) acc[i][j] = zero;
    const int r = tid >> 1, hp = tid & 1;
    const int arow = min(rowBase + r, N - 1);

    for (int k0 = 0; k0 < D_IN; k0 += 32) {
        bf16x8 bfr[4];
        const int G = (k0 >> 3) + lg;
        #pragma unroll
        for (int cb = 0; cb < 4; ++cb)
            bfr[cb] = *(const bf16x8*)&Wf[(((size_t)G * 128) + wc + cb * 16 + l15) * 8];
        __syncthreads();
        #pragma unroll
        for (int g2 = 0; g2 < 2; ++g2) {
            int gg = hp * 2 + g2;
            int k = k0 + gg * 8;
            uint4 w = *(const uint4*)(Abf + (size_t)arow * D_IN + k);
            *(uint4*)&As[(((size_t)gg * 128) + r) * 8] = w;
        }
        __syncthreads();
        #pragma unroll
        for (int rb = 0; rb < 4; ++rb) {
            bf16x8 afr = *(const bf16x8*)&As[(((size_t)lg * 128) + wr + rb * 16 + l15) * 8];
            #pragma unroll
            for (int cb = 0; cb < 4; ++cb)
                acc[rb][cb] = __builtin_amdgcn_mfma_f32_16x16x32_bf16(afr, bfr[cb], acc[rb][cb], 0, 0, 0);
        }
    }
    #pragma unroll
    for (int cb = 0; cb < 4; ++cb) {
        int col = wc + cb * 16 + l15;
        float bvv = bias[col];
        #pragma unroll
        for (int rb = 0; rb < 4; ++rb)
            #pragma unroll
            for (int q = 0; q < 4; ++q) {
                int row = rowBase + wr + rb * 16 + lg * 4 + q;
                if (row < N) C[(size_t)row * D_EMB + col] = f2bf(fmaxf(acc[rb][cb][q] + bvv, 0.f));
            }
    }
}

// ---------------------------------------------------------------------------
// Fused GIN layer (round-6 form: aggh from global, GEMM1+GEMM2+LN in one)
// ---------------------------------------------------------------------------
__global__ __launch_bounds__(256) void gin_layer_k(
    const unsigned short* __restrict__ xb, const unsigned short* __restrict__ hbi,
    const float* __restrict__ aggx, const float* __restrict__ aggh, const float* __restrict__ epsp,
    const unsigned short* __restrict__ W1f, const float* __restrict__ b1,
    const unsigned short* __restrict__ W2f, const float* __restrict__ b2,
    const float* __restrict__ lng, const float* __restrict__ lnb,
    unsigned short* __restrict__ hbo, int N) {
    __shared__ unsigned short As[4 * 128 * 8];
    __shared__ unsigned short T1[16 * 128 * 8];
    __shared__ float rsum[2 * 128];
    __shared__ float rsq[2 * 128];

    const int tid = threadIdx.x;
    const int wid = tid >> 6, lane = tid & 63;
    const int l15 = lane & 15, lg = lane >> 4;
    const int rowBase = blockIdx.x * 128;
    const int wr = (wid >> 1) * 64, wc = (wid & 1) * 64;
    const int wh = wid & 1;

    f32x4 zero = {0.f, 0.f, 0.f, 0.f};
    f32x4 acc[4][4];
    #pragma unroll
    for (int i = 0; i < 4; ++i)
        #pragma unroll
        for (int j = 0; j < 4; ++j) acc[i][j] = zero;

    const float es = 1.0f + epsp[0];
    const int r = tid >> 1, hp = tid & 1;
    const int arow = min(rowBase + r, N - 1);

    for (int k0 = 0; k0 < GI; k0 += 32) {
        bf16x8 bfr[4];
        const int G = (k0 >> 3) + lg;
        #pragma unroll
        for (int cb = 0; cb < 4; ++cb)
            bfr[cb] = *(const bf16x8*)&W1f[(((size_t)G * 128) + wc + cb * 16 + l15) * 8];
        __syncthreads();
        #pragma unroll
        for (int g2 = 0; g2 < 2; ++g2) {
            int gg = hp * 2 + g2;
            int k = k0 + gg * 8;
            float f[8], ga[8];
            if (k < D_IN) {
                uint4 xv = *(const uint4*)(xb + (size_t)arow * D_IN + k);
                const float* gp = aggx + (size_t)arow * D_IN + k;
                float4 g0 = *(const float4*)gp, g1 = *(const float4*)(gp + 4);
                f[0] = bflo(xv.x); f[1] = bfhi(xv.x); f[2] = bflo(xv.y); f[3] = bfhi(xv.y);
                f[4] = bflo(xv.z); f[5] = bfhi(xv.z); f[6] = bflo(xv.w); f[7] = bfhi(xv.w);
                ga[0] = g0.x; ga[1] = g0.y; ga[2] = g0.z; ga[3] = g0.w;
                ga[4] = g1.x; ga[5] = g1.y; ga[6] = g1.z; ga[7] = g1.w;
            } else {
                int kk = k - D_IN;
                uint4 hv = *(const uint4*)(hbi + (size_t)arow * D_EMB + kk);
                const float* gp = aggh + (size_t)arow * D_EMB + kk;
                float4 g0 = *(const float4*)gp, g1 = *(const float4*)(gp + 4);
                f[0] = bflo(hv.x); f[1] = bfhi(hv.x); f[2] = bflo(hv.y); f[3] = bfhi(hv.y);
                f[4] = bflo(hv.z); f[5] = bfhi(hv.z); f[6] = bflo(hv.w); f[7] = bfhi(hv.w);
                ga[0] = g0.x; ga[1] = g0.y; ga[2] = g0.z; ga[3] = g0.w;
                ga[4] = g1.x; ga[5] = g1.y; ga[6] = g1.z; ga[7] = g1.w;
            }
            unsigned short o[8];
            #pragma unroll
            for (int i = 0; i < 8; ++i) o[i] = f2bf(fmaf(es, f[i], ga[i]));
            *(uint4*)&As[(((size_t)gg * 128) + r) * 8] =
                make_uint4(pk2(o[0], o[1]), pk2(o[2], o[3]), pk2(o[4], o[5]), pk2(o[6], o[7]));
        }
        __syncthreads();
        #pragma unroll
        for (int rb = 0; rb < 4; ++rb) {
            bf16x8 afr = *(const bf16x8*)&As[(((size_t)lg * 128) + wr + rb * 16 + l15) * 8];
            #pragma unroll
            for (int cb = 0; cb < 4; ++cb)
                acc[rb][cb] = __builtin_amdgcn_mfma_f32_16x16x32_bf16(afr, bfr[cb], acc[rb][cb], 0, 0, 0);
        }
    }

    #pragma unroll
    for (int cb = 0; cb < 4; ++cb) {
        int col = wc + cb * 16 + l15;
        float bvv = b1[col];
        #pragma unroll
        for (int rb = 0; rb < 4; ++rb)
            #pragma unroll
            for (int q = 0; q < 4; ++q) {
                int row = wr + rb * 16 + lg * 4 + q;
                float v = fmaxf(acc[rb][cb][q] + bvv, 0.f);
                T1[(((size_t)(col >> 3) * 128) + row) * 8 + (col & 7)] = f2bf(v);
            }
    }
    __syncthreads();

    f32x4 acc2[4][4];
    #pragma unroll
    for (int i = 0; i < 4; ++i)
        #pragma unroll
        for (int j = 0; j < 4; ++j) acc2[i][j] = zero;
    for (int k0 = 0; k0 < D_EMB; k0 += 32) {
        bf16x8 bfr[4];
        const int G = (k0 >> 3) + lg;
        #pragma unroll
        for (int cb = 0; cb < 4; ++cb)
            bfr[cb] = *(const bf16x8*)&W2f[(((size_t)G * 128) + wc + cb * 16 + l15) * 8];
        #pragma unroll
        for (int rb = 0; rb < 4; ++rb) {
            bf16x8 afr = *(const bf16x8*)&T1[(((size_t)G * 128) + wr + rb * 16 + l15) * 8];
            #pragma unroll
            for (int cb = 0; cb < 4; ++cb)
                acc2[rb][cb] = __builtin_amdgcn_mfma_f32_16x16x32_bf16(afr, bfr[cb], acc2[rb][cb], 0, 0, 0);
        }
    }

    ln_epilogue<0, 1>(acc2, b2, lng, lnb, hbo, rowBase, wr, wc, lg, l15, wh, rsum, rsq, N);
}

// ---------------------------------------------------------------------------
// Fused FC + LN
// ---------------------------------------------------------------------------
template <int RELU, int ELU>
__global__ __launch_bounds__(256) void fc_ln_k(
    const unsigned short* __restrict__ Abf, const unsigned short* __restrict__ Wf,
    const float* __restrict__ bias, const float* __restrict__ g, const float* __restrict__ b,
    unsigned short* __restrict__ out, int N) {
    __shared__ unsigned short As[4 * 128 * 8];
    __shared__ float rsum[2 * 128];
    __shared__ float rsq[2 * 128];
    const int tid = threadIdx.x;
    const int wid = tid >> 6, lane = tid & 63;
    const int l15 = lane & 15, lg = lane >> 4;
    const int rowBase = blockIdx.x * 128;
    const int wr = (wid >> 1) * 64, wc = (wid & 1) * 64;
    const int wh = wid & 1;
    f32x4 zero = {0.f, 0.f, 0.f, 0.f};
    f32x4 acc[4][4];
    #pragma unroll
    for (int i = 0; i < 4; ++i)
        #pragma unroll
        for (int j = 0; j < 4; ++j) acc[i][j] = zero;
    const int r = tid >> 1, hp = tid & 1;
    const int arow = min(rowBase + r, N - 1);

    for (int k0 = 0; k0 < D_EMB; k0 += 32) {
        bf16x8 bfr[4];
        const int G = (k0 >> 3) + lg;
        #pragma unroll
        for (int cb = 0; cb < 4; ++cb)
            bfr[cb] = *(const bf16x8*)&Wf[(((size_t)G * 128) + wc + cb * 16 + l15) * 8];
        __syncthreads();
        #pragma unroll
        for (int g2 = 0; g2 < 2; ++g2) {
            int gg = hp * 2 + g2;
            int k = k0 + gg * 8;
            uint4 w = *(const uint4*)(Abf + (size_t)arow * D_EMB + k);
            *(uint4*)&As[(((size_t)gg * 128) + r) * 8] = w;
        }
        __syncthreads();
        #pragma unroll
        for (int rb = 0; rb < 4; ++rb) {
            bf16x8 afr = *(const bf16x8*)&As[(((size_t)lg * 128) + wr + rb * 16 + l15) * 8];
            #pragma unroll
            for (int cb = 0; cb < 4; ++cb)
                acc[rb][cb] = __builtin_amdgcn_mfma_f32_16x16x32_bf16(afr, bfr[cb], acc[rb][cb], 0, 0, 0);
        }
    }
    ln_epilogue<RELU, ELU>(acc, bias, g, b, out, rowBase, wr, wc, lg, l15, wh, rsum, rsq, N);
}

// ---------------------------------------------------------------------------
// Graph segment bounds, then 8-way-split mean pool
// ---------------------------------------------------------------------------
__global__ __launch_bounds__(256) void bounds_k(const int* __restrict__ batch, int* __restrict__ bounds,
                                                int N, int B) {
    int i = blockIdx.x * 256 + threadIdx.x;
    if (i <= B) {
        int lo = 0, hi = N;
        while (lo < hi) { int m = (lo + hi) >> 1; if (batch[m] < i) lo = m + 1; else hi = m; }
        bounds[i] = lo;
    }
}

__global__ __launch_bounds__(128) void pool_part_k(const unsigned short* __restrict__ ge,
                                                   const int* __restrict__ bounds,
                                                   float* __restrict__ gemb) {
    int b = blockIdx.x >> 3;
    int s = blockIdx.x & 7;
    int start = bounds[b], end = bounds[b + 1];
    int len = end - start;
    int c0 = start + (int)(((long long)len * s) >> 3);
    int c1 = start + (int)(((long long)len * (s + 1)) >> 3);
    if (c1 <= c0) return;
    int col = threadIdx.x;
    float sum = 0.f;
    for (int n = c0; n < c1; ++n)
        sum += __uint_as_float((unsigned int)ge[(size_t)n * D_EMB + col] << 16);
    atomicAdd(&gemb[(size_t)b * D_EMB + col], sum);
}

// ---------------------------------------------------------------------------
// Node decoder: per-thread MLP [x fp32 | node_emb bf16](192) -> 32 -> 8 -> 1
// ---------------------------------------------------------------------------
__global__ __launch_bounds__(256) void node_dec_k(
    const float* __restrict__ x, const unsigned short* __restrict__ ne,
    const float* __restrict__ W1, const float* __restrict__ b1,
    const float* __restrict__ W2, const float* __restrict__ b2,
    const float* __restrict__ W3, const float* __restrict__ b3,
    float* __restrict__ out, int N) {
    __shared__ float W1s[GI * H1];
    __shared__ float W2s[H1 * H2];
    __shared__ float W3s[H2];
    __shared__ float b1s[H1], b2s[H2];
    for (int i = threadIdx.x; i < GI * H1; i += 256) W1s[i] = W1[i];
    if (threadIdx.x < H1 * H2) W2s[threadIdx.x] = W2[threadIdx.x];
    if (threadIdx.x < H2) { W3s[threadIdx.x] = W3[threadIdx.x]; b2s[threadIdx.x] = b2[threadIdx.x]; }
    if (threadIdx.x < H1) b1s[threadIdx.x] = b1[threadIdx.x];
    __syncthreads();
    int n = blockIdx.x * 256 + threadIdx.x;
    if (n >= N) return;
    float acc[H1];
    #pragma unroll
    for (int j = 0; j < H1; ++j) acc[j] = b1s[j];
    const float4* xr = (const float4*)(x + (size_t)n * D_IN);
    #pragma unroll 4
    for (int q = 0; q < D_IN / 4; ++q) {
        float4 v = xr[q];
        int k = q * 4;
        #pragma unroll
        for (int j = 0; j < H1; ++j) acc[j] = fmaf(v.x, W1s[(k + 0) * H1 + j], acc[j]);
        #pragma unroll
        for (int j = 0; j < H1; ++j) acc[j] = fmaf(v.y, W1s[(k + 1) * H1 + j], acc[j]);
        #pragma unroll
        for (int j = 0; j < H1; ++j) acc[j] = fmaf(v.z, W1s[(k + 2) * H1 + j], acc[j]);
        #pragma unroll
        for (int j = 0; j < H1; ++j) acc[j] = fmaf(v.w, W1s[(k + 3) * H1 + j], acc[j]);
    }
    const uint4* nr = (const uint4*)(ne + (size_t)n * D_EMB);
    #pragma unroll 4
    for (int q = 0; q < 16; ++q) {
        uint4 v = nr[q];
        float f[8] = {bflo(v.x), bfhi(v.x), bflo(v.y), bfhi(v.y),
                      bflo(v.z), bfhi(v.z), bflo(v.w), bfhi(v.w)};
        int k = D_IN + q * 8;
        #pragma unroll
        for (int e = 0; e < 8; ++e) {
            #pragma unroll
            for (int j = 0; j < H1; ++j) acc[j] = fmaf(f[e], W1s[(k + e) * H1 + j], acc[j]);
        }
    }
    #pragma unroll
    for (int j = 0; j < H1; ++j) acc[j] = fmaxf(acc[j], 0.f);
    float a2[H2];
    #pragma unroll
    for (int m = 0; m < H2; ++m) a2[m] = b2s[m];
    #pragma unroll
    for (int j = 0; j < H1; ++j)
        #pragma unroll
        for (int m = 0; m < H2; ++m) a2[m] = fmaf(acc[j], W2s[j * H2 + m], a2[m]);
    float o = b3[0];
    #pragma unroll
    for (int m = 0; m < H2; ++m) o = fmaf(fmaxf(a2[m], 0.f), W3s[m], o);
    out[n] = o;
}

// ---------------------------------------------------------------------------
// Graph decoder: mean-divide fused (reads summed gemb + bounds)
// ---------------------------------------------------------------------------
__global__ __launch_bounds__(256) void graph_dec_k(
    const float* __restrict__ gemb, const int* __restrict__ bounds,
    const float* __restrict__ W1, const float* __restrict__ b1,
    const float* __restrict__ W2, const float* __restrict__ b2,
    const float* __restrict__ W3, const float* __restrict__ b3,
    float* __restrict__ out, int B) {
    __shared__ float W1s[D_EMB * H1];
    __shared__ float W2s[H1 * H2];
    __shared__ float W3s[H2];
    __shared__ float b1s[H1], b2s[H2];
    for (int i = threadIdx.x; i < D_EMB * H1; i += 256) W1s[i] = W1[i];
    if (threadIdx.x < H1 * H2) W2s[threadIdx.x] = W2[threadIdx.x];
    if (threadIdx.x < H2) { W3s[threadIdx.x] = W3[threadIdx.x]; b2s[threadIdx.x] = b2[threadIdx.x]; }
    if (threadIdx.x < H1) b1s[threadIdx.x] = b1[threadIdx.x];
    __syncthreads();
    int gidx = threadIdx.x;
    if (gidx >= B) return;
    int len = bounds[gidx + 1] - bounds[gidx];
    float inv = 1.f / fmaxf((float)len, 1.f);
    float acc[H1];
    #pragma unroll
    for (int j = 0; j < H1; ++j) acc[j] = b1s[j];
    const float4* gr = (const float4*)(gemb + (size_t)gidx * D_EMB);
    for (int q = 0; q < D_EMB / 4; ++q) {
        float4 v = gr[q];
        v.x *= inv; v.y *= inv; v.z *= inv; v.w *= inv;
        int k = q * 4;
        #pragma unroll
        for (int j = 0; j < H1; ++j) acc[j] = fmaf(v.x, W1s[(k + 0) * H1 + j], acc[j]);
        #pragma unroll
        for (int j = 0; j < H1; ++j) acc[j] = fmaf(v.y, W1s[(k + 1) * H1 + j], acc[j]);
        #pragma unroll
        for (int j = 0; j < H1; ++j) acc[j] = fmaf(v.z, W1s[(k + 2) * H1 + j], acc[j]);
        #pragma unroll
        for (int j = 0; j < H1; ++j) acc[j] = fmaf(v.w, W1s[(k + 3) * H1 + j], acc[j]);
    }
    #pragma unroll
    for (int j = 0; j < H1; ++j) acc[j] = fmaxf(acc[j], 0.f);
    float a2[H2];
    #pragma unroll
    for (int m = 0; m < H2; ++m) a2[m] = b2s[m];
    #pragma unroll
    for (int j = 0; j < H1; ++j)
        #pragma unroll
        for (int m = 0; m < H2; ++m) a2[m] = fmaf(acc[j], W2s[j * H2 + m], a2[m]);
    float o = b3[0];
    #pragma unroll
    for (int m = 0; m < H2; ++m) o = fmaf(fmaxf(a2[m], 0.f), W3s[m], o);
    out[gidx] = o;
}

// ---------------------------------------------------------------------------
extern "C" void kernel_launch(void* const* d_in, const int* in_sizes, int n_in,
                              void* d_out, int out_size, void* d_ws, size_t ws_size,
                              hipStream_t stream) {
    const float* x       = (const float*)d_in[0];
    const int*   ei      = (const int*)d_in[1];
    const int*   batch   = (const int*)d_in[2];
    const float* W_in    = (const float*)d_in[3];
    const float* b_in    = (const float*)d_in[4];
    const float* eps     = (const float*)d_in[5];
    const float* mlp_W1  = (const float*)d_in[6];
    const float* mlp_b1  = (const float*)d_in[7];
    const float* mlp_W2  = (const float*)d_in[8];
    const float* mlp_b2  = (const float*)d_in[9];
    const float* ln_g    = (const float*)d_in[10];
    const float* ln_b    = (const float*)d_in[11];
    const float* out_W   = (const float*)d_in[12];
    const float* out_b   = (const float*)d_in[13];
    const float* lnf_g   = (const float*)d_in[14];
    const float* lnf_b   = (const float*)d_in[15];
    const float* graph_W = (const float*)d_in[16];
    const float* graph_b = (const float*)d_in[17];
    const float* gln_g   = (const float*)d_in[18];
    const float* gln_b   = (const float*)d_in[19];
    const float* dW1     = (const float*)d_in[20];
    const float* db1     = (const float*)d_in[21];
    const float* dW2     = (const float*)d_in[22];
    const float* db2     = (const float*)d_in[23];
    const float* dW3     = (const float*)d_in[24];
    const float* db3     = (const float*)d_in[25];
    const float* gW1     = (const float*)d_in[26];
    const float* gb1     = (const float*)d_in[27];
    const float* gW2     = (const float*)d_in[28];
    const float* gb2     = (const float*)d_in[29];
    const float* gW3     = (const float*)d_in[30];
    const float* gb3     = (const float*)d_in[31];
    float* out = (float*)d_out;

    const int N = in_sizes[0] / D_IN;
    const int E = in_sizes[1] / 2;
    const int B = out_size - N;
    const int N8 = (N + 7) / 8;

    const int* esrc = ei;
    const int* edst = ei + E;

    // workspace layout
    size_t off = 0;
    auto alloc = [&](size_t bytes) { size_t o = off; off += (bytes + 255) & ~(size_t)255; return o; };
    char* ws = (char*)d_ws;
    unsigned short* xb  = (unsigned short*)(ws + alloc((size_t)N * D_IN * 2));
    unsigned short* hb0 = (unsigned short*)(ws + alloc((size_t)N * D_EMB * 2));
    unsigned short* hb1 = (unsigned short*)(ws + alloc((size_t)N * D_EMB * 2));
    float* aggx = (float*)(ws + alloc((size_t)N * D_IN * 4));
    float* aggh = (float*)(ws + alloc((size_t)N * D_EMB * 4));
    float* gemb = (float*)(ws + alloc((size_t)B * D_EMB * 4));
    unsigned short* wfpool = (unsigned short*)(ws + alloc((size_t)163840 * 2));
    int* row_ptr = (int*)(ws + alloc((size_t)(N + 1) * 4));
    int* cnt     = (int*)(ws + alloc((size_t)N * 4));
    int* bsum    = (int*)(ws + alloc(512 * 4));
    int* bounds  = (int*)(ws + alloc((size_t)(B + 1) * 4));
    int* csr     = (int*)(ws + alloc((size_t)E * 4));
    (void)ws_size;

    unsigned short* wf_in    = wfpool;
    unsigned short* wf_w1    = wf_in + (size_t)64 * 128;
    unsigned short* wf_w2    = wf_w1 + (size_t)3 * 192 * 128;
    unsigned short* wf_graph = wf_w2 + (size_t)3 * 128 * 128;
    unsigned short* wf_out   = wf_graph + (size_t)128 * 128;

    unsigned short* zb  = hb0;                    // graph-branch LN out (hb0 free after layer 2)
    unsigned short* neb = (unsigned short*)aggh;  // node-branch LN out (aggh free after layer 2)

    const int NB = (N + 255) / 256;
    const int gridEP = 8 * ((E + 1023) / 1024);
    const int gridN4 = (N + 3) / 4;
    const int gridG = (N + 127) / 128;

    // ---- CSR build (XCD-partitioned hist/scatter) ----
    hipMemsetAsync(cnt, 0, (size_t)N * 4, stream);
    hist_part_k<<<gridEP, 256, 0, stream>>>(edst, cnt, E, N8);
    scan1_k<<<NB, 256, 0, stream>>>(cnt, row_ptr, bsum, N);
    scan2_k<<<1, 512, 0, stream>>>(bsum, NB);
    scan3_k<<<(N + 256) / 256, 256, 0, stream>>>(row_ptr, bsum, cnt, N, E);
    scatter_part_k<<<gridEP, 256, 0, stream>>>(esrc, edst, cnt, csr, E, N8);

    // ---- prep: x -> bf16, weights -> fragment pool, graph bounds, gemb zero ----
    xcvt_k<<<(N * D_IN / 4 + 255) / 256, 256, 0, stream>>>(x, xb, N * D_IN / 4);
    wfrag_all_k<<<640, 256, 0, stream>>>(W_in, mlp_W1, mlp_W2, graph_W, out_W,
                                         wf_in, wf_w1, wf_w2, wf_graph, wf_out);
    bounds_k<<<(B + 256) / 256, 256, 0, stream>>>(batch, bounds, N, B);
    hipMemsetAsync(gemb, 0, (size_t)B * D_EMB * 4, stream);

    // ---- x aggregation (layer-invariant) ----
    agg64b_k<<<(N + 7) / 8, 256, 0, stream>>>(xb, row_ptr, csr, aggx, N);

    // ---- encoder ----
    enc_gemm_k<<<gridG, 256, 0, stream>>>(xb, wf_in, b_in, hb0, N);

    // ---- GIN layers ----
    unsigned short* hin = hb0;
    unsigned short* hout = hb1;
    for (int l = 0; l < 3; ++l) {
        agg128b_k<<<gridN4, 256, 0, stream>>>(hin, row_ptr, csr, aggh, N);
        gin_layer_k<<<gridG, 256, 0, stream>>>(xb, hin, aggx, aggh, eps + l,
                                               wf_w1 + (size_t)l * 192 * 128, mlp_b1 + (size_t)l * D_EMB,
                                               wf_w2 + (size_t)l * 128 * 128, mlp_b2 + (size_t)l * D_EMB,
                                               ln_g + (size_t)l * D_EMB, ln_b + (size_t)l * D_EMB,
                                               hout, N);
        unsigned short* t = hin; hin = hout; hout = t;
    }
    // final h in hin (= hb1)

    // ---- graph branch ----
    fc_ln_k<1, 0><<<gridG, 256, 0, stream>>>(hin, wf_graph, graph_b, gln_g, gln_b, zb, N);
    pool_part_k<<<B * 8, 128, 0, stream>>>(zb, bounds, gemb);

    // ---- node branch ----
    fc_ln_k<1, 0><<<gridG, 256, 0, stream>>>(hin, wf_out, out_b, lnf_g, lnf_b, neb, N);

    // ---- decoders ----
    node_dec_k<<<(N + 255) / 256, 256, 0, stream>>>(x, neb, dW1, db1, dW2, db2, dW3, db3, out, N);
    graph_dec_k<<<1, 256, 0, stream>>>(gemb, bounds, gW1, gb1, gW2, gb2, gW3, gb3, out + N, B);
}

// Round 10
// 819.937 us; speedup vs baseline: 1.5954x; 1.0084x over previous
//
#include <hip/hip_runtime.h>
#include <hip/hip_bf16.h>

#define D_IN 64
#define D_EMB 128
#define GI 192           // D_IN + D_EMB
#define H1 32
#define H2 8

typedef __attribute__((ext_vector_type(8))) short bf16x8;
typedef __attribute__((ext_vector_type(4))) float f32x4;

__device__ __forceinline__ unsigned short f2bf(float f) {
    unsigned int u = __float_as_uint(f);
    return (unsigned short)((u + 0x7fffu + ((u >> 16) & 1u)) >> 16);
}
__device__ __forceinline__ float bflo(unsigned int u) { return __uint_as_float(u << 16); }
__device__ __forceinline__ float bfhi(unsigned int u) { return __uint_as_float(u & 0xffff0000u); }
__device__ __forceinline__ unsigned int pk2(unsigned short a, unsigned short b) {
    return (unsigned int)a | ((unsigned int)b << 16);
}

// ---------------------------------------------------------------------------
// CSR build, XCD-partitioned (round-3 notes: merges partial-line writes in L2)
// ---------------------------------------------------------------------------
__global__ __launch_bounds__(256) void hist_part_k(const int* __restrict__ dst, int* __restrict__ cnt,
                                                   int E, int N8) {
    int p = blockIdx.x & 7;
    int base = (blockIdx.x >> 3) * 1024;
    int lo = p * N8, hi = lo + N8;
    #pragma unroll
    for (int t = 0; t < 4; ++t) {
        int e = base + t * 256 + threadIdx.x;
        if (e < E) {
            int d = dst[e];
            if (d >= lo && d < hi) atomicAdd(&cnt[d], 1);
        }
    }
}

__global__ __launch_bounds__(256) void scan1_k(const int* __restrict__ cnt, int* __restrict__ loc,
                                               int* __restrict__ bsum, int N) {
    __shared__ int s[256];
    int tid = threadIdx.x;
    int i = blockIdx.x * 256 + tid;
    int v = (i < N) ? cnt[i] : 0;
    s[tid] = v;
    __syncthreads();
    #pragma unroll
    for (int off = 1; off < 256; off <<= 1) {
        int u = (tid >= off) ? s[tid - off] : 0;
        __syncthreads();
        s[tid] += u;
        __syncthreads();
    }
    int incl = s[tid];
    if (i < N) loc[i] = incl - v;
    if (tid == 255) bsum[blockIdx.x] = incl;
}

__global__ __launch_bounds__(512) void scan2_k(int* __restrict__ bsum, int NB) {
    __shared__ int s[512];
    int tid = threadIdx.x;
    int v = (tid < NB) ? bsum[tid] : 0;
    s[tid] = v;
    __syncthreads();
    #pragma unroll
    for (int off = 1; off < 512; off <<= 1) {
        int u = (tid >= off) ? s[tid - off] : 0;
        __syncthreads();
        s[tid] += u;
        __syncthreads();
    }
    if (tid < NB) bsum[tid] = s[tid] - v;
}

__global__ __launch_bounds__(256) void scan3_k(int* __restrict__ rp, const int* __restrict__ bsum,
                                               int* __restrict__ cursor, int N, int E) {
    int i = blockIdx.x * 256 + threadIdx.x;
    if (i < N) {
        int r = rp[i] + bsum[i >> 8];
        rp[i] = r;
        cursor[i] = r;
    } else if (i == N) {
        rp[N] = E;
    }
}

__global__ __launch_bounds__(256) void scatter_part_k(const int* __restrict__ src, const int* __restrict__ dst,
                                                      int* __restrict__ cursor, int* __restrict__ csr,
                                                      int E, int N8) {
    int p = blockIdx.x & 7;
    int base = (blockIdx.x >> 3) * 1024;
    int lo = p * N8, hi = lo + N8;
    #pragma unroll
    for (int t = 0; t < 4; ++t) {
        int e = base + t * 256 + threadIdx.x;
        if (e < E) {
            int d = dst[e];
            if (d >= lo && d < hi) {
                int s = src[e];
                int pos = atomicAdd(&cursor[d], 1);
                csr[pos] = s;
            }
        }
    }
}

// ---------------------------------------------------------------------------
// Conversions / weight fragment prep
// ---------------------------------------------------------------------------
__global__ __launch_bounds__(256) void xcvt_k(const float* __restrict__ x, unsigned short* __restrict__ xb,
                                              int total4) {
    int i = blockIdx.x * 256 + threadIdx.x;
    if (i < total4) {
        float4 v = ((const float4*)x)[i];
        ((uint2*)xb)[i] = make_uint2(pk2(f2bf(v.x), f2bf(v.y)), pk2(f2bf(v.z), f2bf(v.w)));
    }
}

__global__ __launch_bounds__(256) void wfrag_all_k(
    const float* __restrict__ W_in, const float* __restrict__ mlp_W1, const float* __restrict__ mlp_W2,
    const float* __restrict__ graph_W, const float* __restrict__ out_W,
    unsigned short* __restrict__ wf_in, unsigned short* __restrict__ wf_w1,
    unsigned short* __restrict__ wf_w2, unsigned short* __restrict__ wf_graph,
    unsigned short* __restrict__ wf_out) {
    int idx = blockIdx.x * 256 + threadIdx.x;
    const float* src;
    unsigned short* dst;
    int local;
    if (idx < 8192) { src = W_in; dst = wf_in; local = idx; }
    else if (idx < 81920) { int t = idx - 8192; int l = t / 24576; local = t - l * 24576;
                            src = mlp_W1 + (size_t)l * 24576; dst = wf_w1 + (size_t)l * 24576; }
    else if (idx < 131072) { int t = idx - 81920; int l = t / 16384; local = t - l * 16384;
                             src = mlp_W2 + (size_t)l * 16384; dst = wf_w2 + (size_t)l * 16384; }
    else if (idx < 147456) { local = idx - 131072; src = graph_W; dst = wf_graph; }
    else { local = idx - 147456; src = out_W; dst = wf_out; }
    int k = local >> 7, c = local & 127;
    dst[(((size_t)(k >> 3) * 128) + c) * 8 + (k & 7)] = f2bf(src[local]);
}

// ---------------------------------------------------------------------------
// x aggregation (layer-invariant), bf16 output
// ---------------------------------------------------------------------------
__global__ __launch_bounds__(256) void agg64b_k(const unsigned short* __restrict__ xb,
                                                const int* __restrict__ rp, const int* __restrict__ cs,
                                                unsigned short* __restrict__ outb, int N) {
    int n = blockIdx.x * 8 + (threadIdx.x >> 5);
    int lane = threadIdx.x & 31;
    if (n >= N) return;
    int bg = rp[n], e = rp[n + 1];
    const unsigned int* x2 = (const unsigned int*)xb;
    float sx = 0.f, sy = 0.f;
    int j = bg;
    for (; j + 3 < e; j += 4) {
        unsigned int v0 = x2[(size_t)cs[j] * 32 + lane];
        unsigned int v1 = x2[(size_t)cs[j + 1] * 32 + lane];
        unsigned int v2 = x2[(size_t)cs[j + 2] * 32 + lane];
        unsigned int v3 = x2[(size_t)cs[j + 3] * 32 + lane];
        sx += bflo(v0) + bflo(v1) + bflo(v2) + bflo(v3);
        sy += bfhi(v0) + bfhi(v1) + bfhi(v2) + bfhi(v3);
    }
    for (; j < e; ++j) {
        unsigned int v = x2[(size_t)cs[j] * 32 + lane];
        sx += bflo(v);
        sy += bfhi(v);
    }
    ((unsigned int*)outb)[(size_t)n * 32 + lane] = pk2(f2bf(sx), f2bf(sy));
}

// ---------------------------------------------------------------------------
// h aggregation + GIN-z fold: zh = bf16((1+eps)*h[n] + sum_{neighbors} h)
// (same gather/order as round-6 agg128b; self row is a contiguous read)
// ---------------------------------------------------------------------------
__global__ __launch_bounds__(256) void aggz_k(const unsigned short* __restrict__ hb,
                                              const int* __restrict__ rp, const int* __restrict__ cs,
                                              const float* __restrict__ epsp,
                                              unsigned short* __restrict__ zh, int N) {
    int w = threadIdx.x >> 6, lane = threadIdx.x & 63;
    int n = blockIdx.x * 4 + w;
    if (n >= N) return;
    float es = 1.0f + epsp[0];
    int bg = rp[n], e = rp[n + 1];
    const unsigned int* h2 = (const unsigned int*)hb;
    float sx = 0.f, sy = 0.f;
    int j = bg;
    for (; j + 3 < e; j += 4) {
        unsigned int v0 = h2[(size_t)cs[j] * 64 + lane];
        unsigned int v1 = h2[(size_t)cs[j + 1] * 64 + lane];
        unsigned int v2 = h2[(size_t)cs[j + 2] * 64 + lane];
        unsigned int v3 = h2[(size_t)cs[j + 3] * 64 + lane];
        sx += bflo(v0) + bflo(v1) + bflo(v2) + bflo(v3);
        sy += bfhi(v0) + bfhi(v1) + bfhi(v2) + bfhi(v3);
    }
    for (; j < e; ++j) {
        unsigned int v = h2[(size_t)cs[j] * 64 + lane];
        sx += bflo(v);
        sy += bfhi(v);
    }
    unsigned int hv = h2[(size_t)n * 64 + lane];
    sx = fmaf(es, bflo(hv), sx);
    sy = fmaf(es, bfhi(hv), sy);
    ((unsigned int*)zh)[(size_t)n * 64 + lane] = pk2(f2bf(sx), f2bf(sy));
}

// ---------------------------------------------------------------------------
// Cross-wave LayerNorm epilogue for a 128x128 tile held as 4x4 16x16 C-frags.
// ---------------------------------------------------------------------------
template <int RELU, int ELU>
__device__ __forceinline__ void ln_epilogue(
    f32x4 (&acc)[4][4], const float* __restrict__ bias,
    const float* __restrict__ g, const float* __restrict__ b,
    unsigned short* __restrict__ out,
    int rowBase, int wr, int wc, int lg, int l15, int wh,
    float* rsum, float* rsq, int N) {
    float bv[4], gv[4], bbv[4];
    #pragma unroll
    for (int cb = 0; cb < 4; ++cb) {
        int col = wc + cb * 16 + l15;
        bv[cb] = bias[col];
        gv[cb] = g[col];
        bbv[cb] = b[col];
    }
    float ps[4][4], pq[4][4];
    #pragma unroll
    for (int rb = 0; rb < 4; ++rb)
        #pragma unroll
        for (int q = 0; q < 4; ++q) {
            float s = 0.f, sq = 0.f;
            #pragma unroll
            for (int cb = 0; cb < 4; ++cb) {
                float v = acc[rb][cb][q] + bv[cb];
                if (RELU) v = fmaxf(v, 0.f);
                s += v;
                sq += v * v;
            }
            ps[rb][q] = s;
            pq[rb][q] = sq;
        }
    #pragma unroll
    for (int m = 1; m < 16; m <<= 1) {
        #pragma unroll
        for (int rb = 0; rb < 4; ++rb)
            #pragma unroll
            for (int q = 0; q < 4; ++q) {
                ps[rb][q] += __shfl_xor(ps[rb][q], m, 64);
                pq[rb][q] += __shfl_xor(pq[rb][q], m, 64);
            }
    }
    if (l15 == 0) {
        #pragma unroll
        for (int rb = 0; rb < 4; ++rb)
            #pragma unroll
            for (int q = 0; q < 4; ++q) {
                int row = wr + rb * 16 + lg * 4 + q;
                rsum[wh * 128 + row] = ps[rb][q];
                rsq[wh * 128 + row] = pq[rb][q];
            }
    }
    __syncthreads();
    #pragma unroll
    for (int rb = 0; rb < 4; ++rb)
        #pragma unroll
        for (int q = 0; q < 4; ++q) {
            int row = wr + rb * 16 + lg * 4 + q;
            float st = rsum[row] + rsum[128 + row];
            float sqt = rsq[row] + rsq[128 + row];
            float mu = st * (1.f / 128.f);
            float var = sqt * (1.f / 128.f) - mu * mu;
            float rs = rsqrtf(var + 1e-5f);
            int grow = rowBase + row;
            if (grow < N) {
                #pragma unroll
                for (int cb = 0; cb < 4; ++cb) {
                    float v = acc[rb][cb][q] + bv[cb];
                    if (RELU) v = fmaxf(v, 0.f);
                    float y = (v - mu) * rs * gv[cb] + bbv[cb];
                    if (ELU) y = y > 0.f ? y : expm1f(y);
                    out[(size_t)grow * D_EMB + wc + cb * 16 + l15] = f2bf(y);
                }
            }
        }
}

// ---------------------------------------------------------------------------
// Encoder GEMM: hb = relu(xb @ W_in + b_in), K=64, bf16 MFMA
// ---------------------------------------------------------------------------
__global__ __launch_bounds__(256) void enc_gemm_k(
    const unsigned short* __restrict__ Abf, const unsigned short* __restrict__ Wf,
    const float* __restrict__ bias, unsigned short* __restrict__ C, int N) {
    __shared__ unsigned short As[4 * 128 * 8];
    const int tid = threadIdx.x;
    const int wid = tid >> 6, lane = tid & 63;
    const int l15 = lane & 15, lg = lane >> 4;
    const int rowBase = blockIdx.x * 128;
    const int wr = (wid >> 1) * 64, wc = (wid & 1) * 64;
    f32x4 zero = {0.f, 0.f, 0.f, 0.f};
    f32x4 acc[4][4];
    #pragma unroll
    for (int i = 0; i < 4; ++i)
        #pragma unroll
        for (int j = 0; j < 4; ++j) acc[i][j] = zero;
    const int r = tid >> 1, hp = tid & 1;
    const int arow = min(rowBase + r, N - 1);

    for (int k0 = 0; k0 < D_IN; k0 += 32) {
        bf16x8 bfr[4];
        const int G = (k0 >> 3) + lg;
        #pragma unroll
        for (int cb = 0; cb < 4; ++cb)
            bfr[cb] = *(const bf16x8*)&Wf[(((size_t)G * 128) + wc + cb * 16 + l15) * 8];
        __syncthreads();
        #pragma unroll
        for (int g2 = 0; g2 < 2; ++g2) {
            int gg = hp * 2 + g2;
            int k = k0 + gg * 8;
            uint4 w = *(const uint4*)(Abf + (size_t)arow * D_IN + k);
            *(uint4*)&As[(((size_t)gg * 128) + r) * 8] = w;
        }
        __syncthreads();
        #pragma unroll
        for (int rb = 0; rb < 4; ++rb) {
            bf16x8 afr = *(const bf16x8*)&As[(((size_t)lg * 128) + wr + rb * 16 + l15) * 8];
            #pragma unroll
            for (int cb = 0; cb < 4; ++cb)
                acc[rb][cb] = __builtin_amdgcn_mfma_f32_16x16x32_bf16(afr, bfr[cb], acc[rb][cb], 0, 0, 0);
        }
    }
    #pragma unroll
    for (int cb = 0; cb < 4; ++cb) {
        int col = wc + cb * 16 + l15;
        float bvv = bias[col];
        #pragma unroll
        for (int rb = 0; rb < 4; ++rb)
            #pragma unroll
            for (int q = 0; q < 4; ++q) {
                int row = rowBase + wr + rb * 16 + lg * 4 + q;
                if (row < N) C[(size_t)row * D_EMB + col] = f2bf(fmaxf(acc[rb][cb][q] + bvv, 0.f));
            }
    }
}

// ---------------------------------------------------------------------------
// Fused GIN layer: A-operand from xb/aggxb (k<64, bf16+bf16 fmaf) and zh
// (k>=64, straight uint4 copy). GEMM1 -> T1 -> GEMM2 -> LN+ELU.
// ---------------------------------------------------------------------------
__global__ __launch_bounds__(256) void gin_layer_k(
    const unsigned short* __restrict__ xb, const unsigned short* __restrict__ aggxb,
    const unsigned short* __restrict__ zhb, const float* __restrict__ epsp,
    const unsigned short* __restrict__ W1f, const float* __restrict__ b1,
    const unsigned short* __restrict__ W2f, const float* __restrict__ b2,
    const float* __restrict__ lng, const float* __restrict__ lnb,
    unsigned short* __restrict__ hbo, int N) {
    __shared__ unsigned short As[4 * 128 * 8];
    __shared__ unsigned short T1[16 * 128 * 8];
    __shared__ float rsum[2 * 128];
    __shared__ float rsq[2 * 128];

    const int tid = threadIdx.x;
    const int wid = tid >> 6, lane = tid & 63;
    const int l15 = lane & 15, lg = lane >> 4;
    const int rowBase = blockIdx.x * 128;
    const int wr = (wid >> 1) * 64, wc = (wid & 1) * 64;
    const int wh = wid & 1;

    f32x4 zero = {0.f, 0.f, 0.f, 0.f};
    f32x4 acc[4][4];
    #pragma unroll
    for (int i = 0; i < 4; ++i)
        #pragma unroll
        for (int j = 0; j < 4; ++j) acc[i][j] = zero;

    const float es = 1.0f + epsp[0];
    const int r = tid >> 1, hp = tid & 1;
    const int arow = min(rowBase + r, N - 1);

    for (int k0 = 0; k0 < GI; k0 += 32) {
        bf16x8 bfr[4];
        const int G = (k0 >> 3) + lg;
        #pragma unroll
        for (int cb = 0; cb < 4; ++cb)
            bfr[cb] = *(const bf16x8*)&W1f[(((size_t)G * 128) + wc + cb * 16 + l15) * 8];
        __syncthreads();
        #pragma unroll
        for (int g2 = 0; g2 < 2; ++g2) {
            int gg = hp * 2 + g2;
            int k = k0 + gg * 8;
            uint4 w;
            if (k < D_IN) {
                uint4 xv = *(const uint4*)(xb + (size_t)arow * D_IN + k);
                uint4 av = *(const uint4*)(aggxb + (size_t)arow * D_IN + k);
                unsigned short o[8];
                o[0] = f2bf(fmaf(es, bflo(xv.x), bflo(av.x)));
                o[1] = f2bf(fmaf(es, bfhi(xv.x), bfhi(av.x)));
                o[2] = f2bf(fmaf(es, bflo(xv.y), bflo(av.y)));
                o[3] = f2bf(fmaf(es, bfhi(xv.y), bfhi(av.y)));
                o[4] = f2bf(fmaf(es, bflo(xv.z), bflo(av.z)));
                o[5] = f2bf(fmaf(es, bfhi(xv.z), bfhi(av.z)));
                o[6] = f2bf(fmaf(es, bflo(xv.w), bflo(av.w)));
                o[7] = f2bf(fmaf(es, bfhi(xv.w), bfhi(av.w)));
                w = make_uint4(pk2(o[0], o[1]), pk2(o[2], o[3]), pk2(o[4], o[5]), pk2(o[6], o[7]));
            } else {
                w = *(const uint4*)(zhb + (size_t)arow * D_EMB + (k - D_IN));
            }
            *(uint4*)&As[(((size_t)gg * 128) + r) * 8] = w;
        }
        __syncthreads();
        #pragma unroll
        for (int rb = 0; rb < 4; ++rb) {
            bf16x8 afr = *(const bf16x8*)&As[(((size_t)lg * 128) + wr + rb * 16 + l15) * 8];
            #pragma unroll
            for (int cb = 0; cb < 4; ++cb)
                acc[rb][cb] = __builtin_amdgcn_mfma_f32_16x16x32_bf16(afr, bfr[cb], acc[rb][cb], 0, 0, 0);
        }
    }

    #pragma unroll
    for (int cb = 0; cb < 4; ++cb) {
        int col = wc + cb * 16 + l15;
        float bvv = b1[col];
        #pragma unroll
        for (int rb = 0; rb < 4; ++rb)
            #pragma unroll
            for (int q = 0; q < 4; ++q) {
                int row = wr + rb * 16 + lg * 4 + q;
                float v = fmaxf(acc[rb][cb][q] + bvv, 0.f);
                T1[(((size_t)(col >> 3) * 128) + row) * 8 + (col & 7)] = f2bf(v);
            }
    }
    __syncthreads();

    f32x4 acc2[4][4];
    #pragma unroll
    for (int i = 0; i < 4; ++i)
        #pragma unroll
        for (int j = 0; j < 4; ++j) acc2[i][j] = zero;
    for (int k0 = 0; k0 < D_EMB; k0 += 32) {
        bf16x8 bfr[4];
        const int G = (k0 >> 3) + lg;
        #pragma unroll
        for (int cb = 0; cb < 4; ++cb)
            bfr[cb] = *(const bf16x8*)&W2f[(((size_t)G * 128) + wc + cb * 16 + l15) * 8];
        #pragma unroll
        for (int rb = 0; rb < 4; ++rb) {
            bf16x8 afr = *(const bf16x8*)&T1[(((size_t)G * 128) + wr + rb * 16 + l15) * 8];
            #pragma unroll
            for (int cb = 0; cb < 4; ++cb)
                acc2[rb][cb] = __builtin_amdgcn_mfma_f32_16x16x32_bf16(afr, bfr[cb], acc2[rb][cb], 0, 0, 0);
        }
    }

    ln_epilogue<0, 1>(acc2, b2, lng, lnb, hbo, rowBase, wr, wc, lg, l15, wh, rsum, rsq, N);
}

// ---------------------------------------------------------------------------
// Dual FC+LN: graph branch -> zb, node branch -> neb; hin staged ONCE.
// ---------------------------------------------------------------------------
__global__ __launch_bounds__(256) void fc2_k(
    const unsigned short* __restrict__ Abf,
    const unsigned short* __restrict__ WfG, const float* __restrict__ biasG,
    const float* __restrict__ gG, const float* __restrict__ bG, unsigned short* __restrict__ outG,
    const unsigned short* __restrict__ WfN, const float* __restrict__ biasN,
    const float* __restrict__ gN, const float* __restrict__ bN, unsigned short* __restrict__ outN,
    int N) {
    __shared__ unsigned short As[4 * 128 * 8];
    __shared__ float rsum[2 * 128];
    __shared__ float rsq[2 * 128];
    const int tid = threadIdx.x;
    const int wid = tid >> 6, lane = tid & 63;
    const int l15 = lane & 15, lg = lane >> 4;
    const int rowBase = blockIdx.x * 128;
    const int wr = (wid >> 1) * 64, wc = (wid & 1) * 64;
    const int wh = wid & 1;
    f32x4 zero = {0.f, 0.f, 0.f, 0.f};
    f32x4 accG[4][4], accN[4][4];
    #pragma unroll
    for (int i = 0; i < 4; ++i)
        #pragma unroll
        for (int j = 0; j < 4; ++j) { accG[i][j] = zero; accN[i][j] = zero; }
    const int r = tid >> 1, hp = tid & 1;
    const int arow = min(rowBase + r, N - 1);

    for (int k0 = 0; k0 < D_EMB; k0 += 32) {
        bf16x8 bfrG[4], bfrN[4];
        const int G = (k0 >> 3) + lg;
        #pragma unroll
        for (int cb = 0; cb < 4; ++cb) {
            bfrG[cb] = *(const bf16x8*)&WfG[(((size_t)G * 128) + wc + cb * 16 + l15) * 8];
            bfrN[cb] = *(const bf16x8*)&WfN[(((size_t)G * 128) + wc + cb * 16 + l15) * 8];
        }
        __syncthreads();
        #pragma unroll
        for (int g2 = 0; g2 < 2; ++g2) {
            int gg = hp * 2 + g2;
            int k = k0 + gg * 8;
            uint4 w = *(const uint4*)(Abf + (size_t)arow * D_EMB + k);
            *(uint4*)&As[(((size_t)gg * 128) + r) * 8] = w;
        }
        __syncthreads();
        #pragma unroll
        for (int rb = 0; rb < 4; ++rb) {
            bf16x8 afr = *(const bf16x8*)&As[(((size_t)lg * 128) + wr + rb * 16 + l15) * 8];
            #pragma unroll
            for (int cb = 0; cb < 4; ++cb) {
                accG[rb][cb] = __builtin_amdgcn_mfma_f32_16x16x32_bf16(afr, bfrG[cb], accG[rb][cb], 0, 0, 0);
                accN[rb][cb] = __builtin_amdgcn_mfma_f32_16x16x32_bf16(afr, bfrN[cb], accN[rb][cb], 0, 0, 0);
            }
        }
    }
    ln_epilogue<1, 0>(accG, biasG, gG, bG, outG, rowBase, wr, wc, lg, l15, wh, rsum, rsq, N);
    __syncthreads();   // rsum/rsq reuse barrier between the two epilogues
    ln_epilogue<1, 0>(accN, biasN, gN, bN, outN, rowBase, wr, wc, lg, l15, wh, rsum, rsq, N);
}

// ---------------------------------------------------------------------------
// Graph segment bounds, then 8-way-split mean pool
// ---------------------------------------------------------------------------
__global__ __launch_bounds__(256) void bounds_k(const int* __restrict__ batch, int* __restrict__ bounds,
                                                int N, int B) {
    int i = blockIdx.x * 256 + threadIdx.x;
    if (i <= B) {
        int lo = 0, hi = N;
        while (lo < hi) { int m = (lo + hi) >> 1; if (batch[m] < i) lo = m + 1; else hi = m; }
        bounds[i] = lo;
    }
}

__global__ __launch_bounds__(128) void pool_part_k(const unsigned short* __restrict__ ge,
                                                   const int* __restrict__ bounds,
                                                   float* __restrict__ gemb) {
    int b = blockIdx.x >> 3;
    int s = blockIdx.x & 7;
    int start = bounds[b], end = bounds[b + 1];
    int len = end - start;
    int c0 = start + (int)(((long long)len * s) >> 3);
    int c1 = start + (int)(((long long)len * (s + 1)) >> 3);
    if (c1 <= c0) return;
    int col = threadIdx.x;
    float sum = 0.f;
    for (int n = c0; n < c1; ++n)
        sum += __uint_as_float((unsigned int)ge[(size_t)n * D_EMB + col] << 16);
    atomicAdd(&gemb[(size_t)b * D_EMB + col], sum);
}

// ---------------------------------------------------------------------------
// Node decoder: per-thread MLP [x fp32 | node_emb bf16](192) -> 32 -> 8 -> 1
// ---------------------------------------------------------------------------
__global__ __launch_bounds__(256) void node_dec_k(
    const float* __restrict__ x, const unsigned short* __restrict__ ne,
    const float* __restrict__ W1, const float* __restrict__ b1,
    const float* __restrict__ W2, const float* __restrict__ b2,
    const float* __restrict__ W3, const float* __restrict__ b3,
    float* __restrict__ out, int N) {
    __shared__ float W1s[GI * H1];
    __shared__ float W2s[H1 * H2];
    __shared__ float W3s[H2];
    __shared__ float b1s[H1], b2s[H2];
    for (int i = threadIdx.x; i < GI * H1; i += 256) W1s[i] = W1[i];
    if (threadIdx.x < H1 * H2) W2s[threadIdx.x] = W2[threadIdx.x];
    if (threadIdx.x < H2) { W3s[threadIdx.x] = W3[threadIdx.x]; b2s[threadIdx.x] = b2[threadIdx.x]; }
    if (threadIdx.x < H1) b1s[threadIdx.x] = b1[threadIdx.x];
    __syncthreads();
    int n = blockIdx.x * 256 + threadIdx.x;
    if (n >= N) return;
    float acc[H1];
    #pragma unroll
    for (int j = 0; j < H1; ++j) acc[j] = b1s[j];
    const float4* xr = (const float4*)(x + (size_t)n * D_IN);
    #pragma unroll 4
    for (int q = 0; q < D_IN / 4; ++q) {
        float4 v = xr[q];
        int k = q * 4;
        #pragma unroll
        for (int j = 0; j < H1; ++j) acc[j] = fmaf(v.x, W1s[(k + 0) * H1 + j], acc[j]);
        #pragma unroll
        for (int j = 0; j < H1; ++j) acc[j] = fmaf(v.y, W1s[(k + 1) * H1 + j], acc[j]);
        #pragma unroll
        for (int j = 0; j < H1; ++j) acc[j] = fmaf(v.z, W1s[(k + 2) * H1 + j], acc[j]);
        #pragma unroll
        for (int j = 0; j < H1; ++j) acc[j] = fmaf(v.w, W1s[(k + 3) * H1 + j], acc[j]);
    }
    const uint4* nr = (const uint4*)(ne + (size_t)n * D_EMB);
    #pragma unroll 4
    for (int q = 0; q < 16; ++q) {
        uint4 v = nr[q];
        float f[8] = {bflo(v.x), bfhi(v.x), bflo(v.y), bfhi(v.y),
                      bflo(v.z), bfhi(v.z), bflo(v.w), bfhi(v.w)};
        int k = D_IN + q * 8;
        #pragma unroll
        for (int e = 0; e < 8; ++e) {
            #pragma unroll
            for (int j = 0; j < H1; ++j) acc[j] = fmaf(f[e], W1s[(k + e) * H1 + j], acc[j]);
        }
    }
    #pragma unroll
    for (int j = 0; j < H1; ++j) acc[j] = fmaxf(acc[j], 0.f);
    float a2[H2];
    #pragma unroll
    for (int m = 0; m < H2; ++m) a2[m] = b2s[m];
    #pragma unroll
    for (int j = 0; j < H1; ++j)
        #pragma unroll
        for (int m = 0; m < H2; ++m) a2[m] = fmaf(acc[j], W2s[j * H2 + m], a2[m]);
    float o = b3[0];
    #pragma unroll
    for (int m = 0; m < H2; ++m) o = fmaf(fmaxf(a2[m], 0.f), W3s[m], o);
    out[n] = o;
}

// ---------------------------------------------------------------------------
// Graph decoder: mean-divide fused (reads summed gemb + bounds)
// ---------------------------------------------------------------------------
__global__ __launch_bounds__(256) void graph_dec_k(
    const float* __restrict__ gemb, const int* __restrict__ bounds,
    const float* __restrict__ W1, const float* __restrict__ b1,
    const float* __restrict__ W2, const float* __restrict__ b2,
    const float* __restrict__ W3, const float* __restrict__ b3,
    float* __restrict__ out, int B) {
    __shared__ float W1s[D_EMB * H1];
    __shared__ float W2s[H1 * H2];
    __shared__ float W3s[H2];
    __shared__ float b1s[H1], b2s[H2];
    for (int i = threadIdx.x; i < D_EMB * H1; i += 256) W1s[i] = W1[i];
    if (threadIdx.x < H1 * H2) W2s[threadIdx.x] = W2[threadIdx.x];
    if (threadIdx.x < H2) { W3s[threadIdx.x] = W3[threadIdx.x]; b2s[threadIdx.x] = b2[threadIdx.x]; }
    if (threadIdx.x < H1) b1s[threadIdx.x] = b1[threadIdx.x];
    __syncthreads();
    int gidx = threadIdx.x;
    if (gidx >= B) return;
    int len = bounds[gidx + 1] - bounds[gidx];
    float inv = 1.f / fmaxf((float)len, 1.f);
    float acc[H1];
    #pragma unroll
    for (int j = 0; j < H1; ++j) acc[j] = b1s[j];
    const float4* gr = (const float4*)(gemb + (size_t)gidx * D_EMB);
    for (int q = 0; q < D_EMB / 4; ++q) {
        float4 v = gr[q];
        v.x *= inv; v.y *= inv; v.z *= inv; v.w *= inv;
        int k = q * 4;
        #pragma unroll
        for (int j = 0; j < H1; ++j) acc[j] = fmaf(v.x, W1s[(k + 0) * H1 + j], acc[j]);
        #pragma unroll
        for (int j = 0; j < H1; ++j) acc[j] = fmaf(v.y, W1s[(k + 1) * H1 + j], acc[j]);
        #pragma unroll
        for (int j = 0; j < H1; ++j) acc[j] = fmaf(v.z, W1s[(k + 2) * H1 + j], acc[j]);
        #pragma unroll
        for (int j = 0; j < H1; ++j) acc[j] = fmaf(v.w, W1s[(k + 3) * H1 + j], acc[j]);
    }
    #pragma unroll
    for (int j = 0; j < H1; ++j) acc[j] = fmaxf(acc[j], 0.f);
    float a2[H2];
    #pragma unroll
    for (int m = 0; m < H2; ++m) a2[m] = b2s[m];
    #pragma unroll
    for (int j = 0; j < H1; ++j)
        #pragma unroll
        for (int m = 0; m < H2; ++m) a2[m] = fmaf(acc[j], W2s[j * H2 + m], a2[m]);
    float o = b3[0];
    #pragma unroll
    for (int m = 0; m < H2; ++m) o = fmaf(fmaxf(a2[m], 0.f), W3s[m], o);
    out[gidx] = o;
}

// ---------------------------------------------------------------------------
extern "C" void kernel_launch(void* const* d_in, const int* in_sizes, int n_in,
                              void* d_out, int out_size, void* d_ws, size_t ws_size,
                              hipStream_t stream) {
    const float* x       = (const float*)d_in[0];
    const int*   ei      = (const int*)d_in[1];
    const int*   batch   = (const int*)d_in[2];
    const float* W_in    = (const float*)d_in[3];
    const float* b_in    = (const float*)d_in[4];
    const float* eps     = (const float*)d_in[5];
    const float* mlp_W1  = (const float*)d_in[6];
    const float* mlp_b1  = (const float*)d_in[7];
    const float* mlp_W2  = (const float*)d_in[8];
    const float* mlp_b2  = (const float*)d_in[9];
    const float* ln_g    = (const float*)d_in[10];
    const float* ln_b    = (const float*)d_in[11];
    const float* out_W   = (const float*)d_in[12];
    const float* out_b   = (const float*)d_in[13];
    const float* lnf_g   = (const float*)d_in[14];
    const float* lnf_b   = (const float*)d_in[15];
    const float* graph_W = (const float*)d_in[16];
    const float* graph_b = (const float*)d_in[17];
    const float* gln_g   = (const float*)d_in[18];
    const float* gln_b   = (const float*)d_in[19];
    const float* dW1     = (const float*)d_in[20];
    const float* db1     = (const float*)d_in[21];
    const float* dW2     = (const float*)d_in[22];
    const float* db2     = (const float*)d_in[23];
    const float* dW3     = (const float*)d_in[24];
    const float* db3     = (const float*)d_in[25];
    const float* gW1     = (const float*)d_in[26];
    const float* gb1     = (const float*)d_in[27];
    const float* gW2     = (const float*)d_in[28];
    const float* gb2     = (const float*)d_in[29];
    const float* gW3     = (const float*)d_in[30];
    const float* gb3     = (const float*)d_in[31];
    float* out = (float*)d_out;

    const int N = in_sizes[0] / D_IN;
    const int E = in_sizes[1] / 2;
    const int B = out_size - N;
    const int N8 = (N + 7) / 8;

    const int* esrc = ei;
    const int* edst = ei + E;

    // workspace layout
    size_t off = 0;
    auto alloc = [&](size_t bytes) { size_t o = off; off += (bytes + 255) & ~(size_t)255; return o; };
    char* ws = (char*)d_ws;
    unsigned short* xb    = (unsigned short*)(ws + alloc((size_t)N * D_IN * 2));
    unsigned short* hb0   = (unsigned short*)(ws + alloc((size_t)N * D_EMB * 2));
    unsigned short* hb1   = (unsigned short*)(ws + alloc((size_t)N * D_EMB * 2));
    unsigned short* zh    = (unsigned short*)(ws + alloc((size_t)N * D_EMB * 2));
    unsigned short* aggxb = (unsigned short*)(ws + alloc((size_t)N * D_IN * 2));
    float* gemb = (float*)(ws + alloc((size_t)B * D_EMB * 4));
    unsigned short* wfpool = (unsigned short*)(ws + alloc((size_t)163840 * 2));
    int* row_ptr = (int*)(ws + alloc((size_t)(N + 1) * 4));
    int* cnt     = (int*)(ws + alloc((size_t)N * 4));
    int* bsum    = (int*)(ws + alloc(512 * 4));
    int* bounds  = (int*)(ws + alloc((size_t)(B + 1) * 4));
    int* csr     = (int*)(ws + alloc((size_t)E * 4));
    (void)ws_size;

    unsigned short* wf_in    = wfpool;
    unsigned short* wf_w1    = wf_in + (size_t)64 * 128;
    unsigned short* wf_w2    = wf_w1 + (size_t)3 * 192 * 128;
    unsigned short* wf_graph = wf_w2 + (size_t)3 * 128 * 128;
    unsigned short* wf_out   = wf_graph + (size_t)128 * 128;

    const int NB = (N + 255) / 256;
    const int gridEP = 8 * ((E + 1023) / 1024);
    const int gridN4 = (N + 3) / 4;
    const int gridG = (N + 127) / 128;

    // ---- CSR build (XCD-partitioned hist/scatter) ----
    hipMemsetAsync(cnt, 0, (size_t)N * 4, stream);
    hist_part_k<<<gridEP, 256, 0, stream>>>(edst, cnt, E, N8);
    scan1_k<<<NB, 256, 0, stream>>>(cnt, row_ptr, bsum, N);
    scan2_k<<<1, 512, 0, stream>>>(bsum, NB);
    scan3_k<<<(N + 256) / 256, 256, 0, stream>>>(row_ptr, bsum, cnt, N, E);
    scatter_part_k<<<gridEP, 256, 0, stream>>>(esrc, edst, cnt, csr, E, N8);

    // ---- prep ----
    xcvt_k<<<(N * D_IN / 4 + 255) / 256, 256, 0, stream>>>(x, xb, N * D_IN / 4);
    wfrag_all_k<<<640, 256, 0, stream>>>(W_in, mlp_W1, mlp_W2, graph_W, out_W,
                                         wf_in, wf_w1, wf_w2, wf_graph, wf_out);
    bounds_k<<<(B + 256) / 256, 256, 0, stream>>>(batch, bounds, N, B);
    hipMemsetAsync(gemb, 0, (size_t)B * D_EMB * 4, stream);

    // ---- x aggregation (layer-invariant, bf16 out) ----
    agg64b_k<<<(N + 7) / 8, 256, 0, stream>>>(xb, row_ptr, csr, aggxb, N);

    // ---- encoder ----
    enc_gemm_k<<<gridG, 256, 0, stream>>>(xb, wf_in, b_in, hb0, N);

    // ---- GIN layers ----
    unsigned short* hin = hb0;
    unsigned short* hout = hb1;
    for (int l = 0; l < 3; ++l) {
        aggz_k<<<gridN4, 256, 0, stream>>>(hin, row_ptr, csr, eps + l, zh, N);
        gin_layer_k<<<gridG, 256, 0, stream>>>(xb, aggxb, zh, eps + l,
                                               wf_w1 + (size_t)l * 192 * 128, mlp_b1 + (size_t)l * D_EMB,
                                               wf_w2 + (size_t)l * 128 * 128, mlp_b2 + (size_t)l * D_EMB,
                                               ln_g + (size_t)l * D_EMB, ln_b + (size_t)l * D_EMB,
                                               hout, N);
        unsigned short* t = hin; hin = hout; hout = t;
    }
    // final h in hin (= hb1); hb0 and zh free
    unsigned short* zb  = hb0;
    unsigned short* neb = zh;

    // ---- both output branches in one pass over hin ----
    fc2_k<<<gridG, 256, 0, stream>>>(hin,
                                     wf_graph, graph_b, gln_g, gln_b, zb,
                                     wf_out, out_b, lnf_g, lnf_b, neb, N);
    pool_part_k<<<B * 8, 128, 0, stream>>>(zb, bounds, gemb);

    // ---- decoders ----
    node_dec_k<<<(N + 255) / 256, 256, 0, stream>>>(x, neb, dW1, db1, dW2, db2, dW3, db3, out, N);
    graph_dec_k<<<1, 256, 0, stream>>>(gemb, bounds, gW1, gb1, gW2, gb2, gW3, gb3, out + N, B);
}